// Round 1
// baseline (533.809 us; speedup 1.0000x reference)
//
#include <hip/hip_runtime.h>
#include <math.h>

#define N_NODES 50000
#define M_NBR 16
#define D 128
#define E 64

// ---------------------------------------------------------------------------
// K1: LayerNorm.  One wave per row (4 rows / 256-thread block).
// ---------------------------------------------------------------------------
__global__ __launch_bounds__(256) void k_ln(const float* __restrict__ x,
                                            const float* __restrict__ sc,
                                            const float* __restrict__ bi,
                                            float* __restrict__ xn) {
  const int row  = blockIdx.x * 4 + (threadIdx.x >> 6);
  const int lane = threadIdx.x & 63;
  float2 v = ((const float2*)(x + (size_t)row * D))[lane];
  float s = v.x + v.y;
  #pragma unroll
  for (int o = 32; o; o >>= 1) s += __shfl_xor(s, o, 64);
  const float mu = s * (1.0f / 128.0f);
  const float dx = v.x - mu, dy = v.y - mu;
  float q = dx * dx + dy * dy;
  #pragma unroll
  for (int o = 32; o; o >>= 1) q += __shfl_xor(q, o, 64);
  const float r = rsqrtf(q * (1.0f / 128.0f) + 1e-6f);
  float2 o2;
  o2.x = fmaf(dx * r, sc[2 * lane],     bi[2 * lane]);
  o2.y = fmaf(dy * r, sc[2 * lane + 1], bi[2 * lane + 1]);
  ((float2*)(xn + (size_t)row * D))[lane] = o2;
}

// ---------------------------------------------------------------------------
// K2: t1 = xn @ W1[0:128], t2 = xn @ W1[128:256].
// 16 nodes per block; thread t owns output column t (t<128 -> t1, else t2).
// xn reads are wave-uniform (blockIdx-derived) -> scalar loads; W1 column
// reads are coalesced per-lane and L2-resident (W1ab read once per block).
// ---------------------------------------------------------------------------
__global__ __launch_bounds__(256) void k_t12(const float* __restrict__ xn,
                                             const float* __restrict__ W1,
                                             float* __restrict__ t1,
                                             float* __restrict__ t2) {
  const int t  = threadIdx.x;
  const int n0 = blockIdx.x * 16;
  const float* wcol = W1 + (t < 128 ? t : (128 * 128 + (t - 128)));
  float acc[16];
  #pragma unroll
  for (int i = 0; i < 16; ++i) acc[i] = 0.0f;
  for (int k4 = 0; k4 < 32; ++k4) {
    const float w0  = wcol[(size_t)(4 * k4 + 0) * 128];
    const float w1v = wcol[(size_t)(4 * k4 + 1) * 128];
    const float w2v = wcol[(size_t)(4 * k4 + 2) * 128];
    const float w3v = wcol[(size_t)(4 * k4 + 3) * 128];
    #pragma unroll
    for (int i = 0; i < 16; ++i) {
      const float4 a = *(const float4*)(xn + (size_t)(n0 + i) * 128 + 4 * k4);
      acc[i] = fmaf(a.x, w0,  acc[i]);
      acc[i] = fmaf(a.y, w1v, acc[i]);
      acc[i] = fmaf(a.z, w2v, acc[i]);
      acc[i] = fmaf(a.w, w3v, acc[i]);
    }
  }
  float* dst = (t < 128) ? (t1 + (size_t)n0 * 128 + t)
                         : (t2 + (size_t)n0 * 128 + (t - 128));
  #pragma unroll
  for (int i = 0; i < 16; ++i) dst[(size_t)i * 128] = acc[i];
}

// ---------------------------------------------------------------------------
// K3: fused edge GEMM + gather + bias + silu + sum over m.
// 2 nodes per block (one per 2-wave half). W1c [64][128] staged in LDS
// (32 KB); per-lane w reads are 2-way bank aliased (free). nbr_fea reads are
// wave-uniform (readfirstlane'd node) -> scalar pipe. Inner loop ~pure FMA.
// ---------------------------------------------------------------------------
__global__ __launch_bounds__(256) void k_edge(const float* __restrict__ nbr,
                                              const int* __restrict__ idx,
                                              const float* __restrict__ t1,
                                              const float* __restrict__ t2,
                                              const float* __restrict__ W1,
                                              const float* __restrict__ b1,
                                              float* __restrict__ hsum) {
  __shared__ float wlds[64 * 128];
  const int t = threadIdx.x;
  {
    const float4* src = (const float4*)(W1 + 256 * 128);
    float4* dst = (float4*)wlds;
    #pragma unroll
    for (int i = 0; i < 8; ++i) dst[t + 256 * i] = src[t + 256 * i];
  }
  __syncthreads();
  const int d = t & 127;
  int n = blockIdx.x * 2 + (t >> 7);
  n = __builtin_amdgcn_readfirstlane(n);   // provably wave-uniform -> s_loads
  const float* nb = nbr + (size_t)n * (M_NBR * E);
  float acc[16];
  #pragma unroll
  for (int m = 0; m < 16; ++m) acc[m] = 0.0f;
  for (int k4 = 0; k4 < 16; ++k4) {
    const float w0  = wlds[(4 * k4 + 0) * 128 + d];
    const float w1v = wlds[(4 * k4 + 1) * 128 + d];
    const float w2v = wlds[(4 * k4 + 2) * 128 + d];
    const float w3v = wlds[(4 * k4 + 3) * 128 + d];
    #pragma unroll
    for (int m = 0; m < 16; ++m) {
      const float4 a = *(const float4*)(nb + m * E + 4 * k4);
      acc[m] = fmaf(a.x, w0,  acc[m]);
      acc[m] = fmaf(a.y, w1v, acc[m]);
      acc[m] = fmaf(a.z, w2v, acc[m]);
      acc[m] = fmaf(a.w, w3v, acc[m]);
    }
  }
  const float t1v = t1[(size_t)n * 128 + d];
  const float b1v = b1[d];
  float hs = 0.0f;
  #pragma unroll
  for (int m = 0; m < 16; ++m) {
    const int g = idx[n * M_NBR + m];          // uniform -> scalar load
    const float tg = t2[(size_t)g * 128 + d];  // coalesced gather, L2/L3-hot
    const float h = acc[m] + t1v + tg + b1v;
    hs += __fdividef(h, 1.0f + __expf(-h));    // silu
  }
  hsum[(size_t)n * 128 + d] = hs;
}

// ---------------------------------------------------------------------------
// K4: out = x + hsum @ W2 + 16*b2.  8 nodes per block (4 per 2-wave half).
// hsum reads wave-uniform -> scalar; W2 column reads coalesced, L2-hot.
// ---------------------------------------------------------------------------
__global__ __launch_bounds__(256) void k_out(const float* __restrict__ hsum,
                                             const float* __restrict__ W2,
                                             const float* __restrict__ b2,
                                             const float* __restrict__ x,
                                             float* __restrict__ out) {
  const int t = threadIdx.x;
  const int d = t & 127;
  int nb4 = blockIdx.x * 8 + (t >> 7) * 4;
  nb4 = __builtin_amdgcn_readfirstlane(nb4);
  float acc[4] = {0.0f, 0.0f, 0.0f, 0.0f};
  for (int k4 = 0; k4 < 32; ++k4) {
    const float w0  = W2[(size_t)(4 * k4 + 0) * 128 + d];
    const float w1v = W2[(size_t)(4 * k4 + 1) * 128 + d];
    const float w2v = W2[(size_t)(4 * k4 + 2) * 128 + d];
    const float w3v = W2[(size_t)(4 * k4 + 3) * 128 + d];
    #pragma unroll
    for (int i = 0; i < 4; ++i) {
      const float4 a = *(const float4*)(hsum + (size_t)(nb4 + i) * 128 + 4 * k4);
      acc[i] = fmaf(a.x, w0,  acc[i]);
      acc[i] = fmaf(a.y, w1v, acc[i]);
      acc[i] = fmaf(a.z, w2v, acc[i]);
      acc[i] = fmaf(a.w, w3v, acc[i]);
    }
  }
  const float b2v = 16.0f * b2[d];
  #pragma unroll
  for (int i = 0; i < 4; ++i) {
    const size_t o = (size_t)(nb4 + i) * 128 + d;
    out[o] = x[o] + acc[i] + b2v;
  }
}

// ---------------------------------------------------------------------------
extern "C" void kernel_launch(void* const* d_in, const int* in_sizes, int n_in,
                              void* d_out, int out_size, void* d_ws, size_t ws_size,
                              hipStream_t stream) {
  const float* x        = (const float*)d_in[0];
  const float* nbr_fea  = (const float*)d_in[1];
  const int*   nbr_idx  = (const int*)d_in[2];
  const float* ln_scale = (const float*)d_in[3];
  const float* ln_bias  = (const float*)d_in[4];
  const float* W1       = (const float*)d_in[5];
  const float* b1       = (const float*)d_in[6];
  const float* W2       = (const float*)d_in[7];
  const float* b2       = (const float*)d_in[8];
  float* out = (float*)d_out;

  const size_t NF = (size_t)N_NODES * D;
  float* xn   = (float*)d_ws;      // [N,128]
  float* t1   = xn + NF;           // [N,128]
  float* t2   = t1 + NF;           // [N,128]
  float* hsum = xn;                // reuse xn region (dead after k_t12)

  k_ln  <<<N_NODES / 4,  256, 0, stream>>>(x, ln_scale, ln_bias, xn);
  k_t12 <<<N_NODES / 16, 256, 0, stream>>>(xn, W1, t1, t2);
  k_edge<<<N_NODES / 2,  256, 0, stream>>>(nbr_fea, nbr_idx, t1, t2, W1, b1, hsum);
  k_out <<<N_NODES / 8,  256, 0, stream>>>(hsum, W2, b2, x, out);
}

// Round 4
// 282.321 us; speedup vs baseline: 1.8908x; 1.8908x over previous
//
#include <hip/hip_runtime.h>
#include <math.h>

#define N_NODES 50000
#define M_NBR 16
#define D 128
#define E 64

typedef __attribute__((ext_vector_type(8))) __bf16 bf16x8;
typedef __attribute__((ext_vector_type(4))) float f32x4;

// ---------------------------------------------------------------------------
// K1: LayerNorm.  One wave per row (4 rows / 256-thread block).
// ---------------------------------------------------------------------------
__global__ __launch_bounds__(256) void k_ln(const float* __restrict__ x,
                                            const float* __restrict__ sc,
                                            const float* __restrict__ bi,
                                            float* __restrict__ xn) {
  const int row  = blockIdx.x * 4 + (threadIdx.x >> 6);
  const int lane = threadIdx.x & 63;
  float2 v = ((const float2*)(x + (size_t)row * D))[lane];
  float s = v.x + v.y;
  #pragma unroll
  for (int o = 32; o; o >>= 1) s += __shfl_xor(s, o, 64);
  const float mu = s * (1.0f / 128.0f);
  const float dx = v.x - mu, dy = v.y - mu;
  float q = dx * dx + dy * dy;
  #pragma unroll
  for (int o = 32; o; o >>= 1) q += __shfl_xor(q, o, 64);
  const float r = rsqrtf(q * (1.0f / 128.0f) + 1e-6f);
  float2 o2;
  o2.x = fmaf(dx * r, sc[2 * lane],     bi[2 * lane]);
  o2.y = fmaf(dy * r, sc[2 * lane + 1], bi[2 * lane + 1]);
  ((float2*)(xn + (size_t)row * D))[lane] = o2;
}

// ---------------------------------------------------------------------------
// K2: t1 = xn @ W1[0:128] (fp32), t2b = bf16(xn @ W1[128:256]).
// 16 nodes per block; thread t owns output column t (t<128 -> t1, else t2b).
// ---------------------------------------------------------------------------
__global__ __launch_bounds__(256) void k_t12(const float* __restrict__ xn,
                                             const float* __restrict__ W1,
                                             float* __restrict__ t1,
                                             __bf16* __restrict__ t2b) {
  const int t  = threadIdx.x;
  const int n0 = blockIdx.x * 16;
  const float* wcol = W1 + (t < 128 ? t : (128 * 128 + (t - 128)));
  float acc[16];
  #pragma unroll
  for (int i = 0; i < 16; ++i) acc[i] = 0.0f;
  for (int k4 = 0; k4 < 32; ++k4) {
    const float w0  = wcol[(size_t)(4 * k4 + 0) * 128];
    const float w1v = wcol[(size_t)(4 * k4 + 1) * 128];
    const float w2v = wcol[(size_t)(4 * k4 + 2) * 128];
    const float w3v = wcol[(size_t)(4 * k4 + 3) * 128];
    #pragma unroll
    for (int i = 0; i < 16; ++i) {
      const float4 a = *(const float4*)(xn + (size_t)(n0 + i) * 128 + 4 * k4);
      acc[i] = fmaf(a.x, w0,  acc[i]);
      acc[i] = fmaf(a.y, w1v, acc[i]);
      acc[i] = fmaf(a.z, w2v, acc[i]);
      acc[i] = fmaf(a.w, w3v, acc[i]);
    }
  }
  if (t < 128) {
    #pragma unroll
    for (int i = 0; i < 16; ++i) t1[(size_t)(n0 + i) * 128 + t] = acc[i];
  } else {
    #pragma unroll
    for (int i = 0; i < 16; ++i)
      t2b[(size_t)(n0 + i) * 128 + (t - 128)] = (__bf16)acc[i];
  }
}

// ---------------------------------------------------------------------------
// K3: edge GEMM via bf16 MFMA + gather + silu + m-sum.  One wave per node
// per pass; 16 edges = MFMA M dimension.  W1c held in B-fragments (64 VGPR,
// no LDS).  A: nbr fp32 load -> bf16 cvt.  Epilogue: +t1 +t2b[gather] +b1,
// silu, shfl-reduce over edge groups.
//   mfma_f32_16x16x32_bf16 layouts: A row=l&15, k=(l>>4)*8+j; B col=l&15,
//   k=(l>>4)*8+j; D col=l&15 (=d), row=(l>>4)*4+j (=edge m).
// ---------------------------------------------------------------------------
__global__ __launch_bounds__(256) void k_edge(const float* __restrict__ nbr,
                                              const int* __restrict__ idx,
                                              const float* __restrict__ t1,
                                              const __bf16* __restrict__ t2b,
                                              const float* __restrict__ W1,
                                              const float* __restrict__ b1,
                                              float* __restrict__ hsum) {
  const int lane = threadIdx.x & 63;
  const int wid  = threadIdx.x >> 6;
  const int r    = lane & 15;   // A row (edge) for loads; D col (d) in epilogue
  const int c    = lane >> 4;   // k-chunk; D row-group in epilogue
  const float* W1c = W1 + 256 * 128;

  // B fragments for all 8 d-tiles x 2 k-steps (loaded once, L2-hot).
  bf16x8 bfrag[8][2];
  #pragma unroll
  for (int dt = 0; dt < 8; ++dt) {
    #pragma unroll
    for (int ko = 0; ko < 2; ++ko) {
      #pragma unroll
      for (int j = 0; j < 8; ++j) {
        const int k = ko * 32 + c * 8 + j;
        bfrag[dt][ko][j] = (__bf16)W1c[k * 128 + dt * 16 + r];
      }
    }
  }
  float b1v[8];
  #pragma unroll
  for (int dt = 0; dt < 8; ++dt) b1v[dt] = b1[dt * 16 + r];

  const int node0 = (blockIdx.x * 4 + wid) * 16;
  for (int ni = 0; ni < 16; ++ni) {
    const int n = node0 + ni;
    if (n >= N_NODES) break;                       // uniform per wave

    // A fragments: edge row r, k-chunk c -> 8 consecutive k per ko.
    const float* arow = nbr + (size_t)n * (M_NBR * E) + r * E + c * 8;
    bf16x8 af[2];
    #pragma unroll
    for (int ko = 0; ko < 2; ++ko) {
      const float4 lo = *(const float4*)(arow + ko * 32);
      const float4 hi = *(const float4*)(arow + ko * 32 + 4);
      af[ko][0] = (__bf16)lo.x; af[ko][1] = (__bf16)lo.y;
      af[ko][2] = (__bf16)lo.z; af[ko][3] = (__bf16)lo.w;
      af[ko][4] = (__bf16)hi.x; af[ko][5] = (__bf16)hi.y;
      af[ko][6] = (__bf16)hi.z; af[ko][7] = (__bf16)hi.w;
    }

    f32x4 acc[8];
    #pragma unroll
    for (int dt = 0; dt < 8; ++dt) acc[dt] = (f32x4){0.f, 0.f, 0.f, 0.f};
    #pragma unroll
    for (int dt = 0; dt < 8; ++dt) {
      acc[dt] = __builtin_amdgcn_mfma_f32_16x16x32_bf16(af[0], bfrag[dt][0], acc[dt], 0, 0, 0);
      acc[dt] = __builtin_amdgcn_mfma_f32_16x16x32_bf16(af[1], bfrag[dt][1], acc[dt], 0, 0, 0);
    }

    // Epilogue: this lane's 4 edges are m = c*4 + j, its d = dt*16 + r.
    const int4 gi = *(const int4*)(idx + n * M_NBR + c * 4);
    float ssum[8];
    #pragma unroll
    for (int dt = 0; dt < 8; ++dt) {
      const int d = dt * 16 + r;
      const float t1v = t1[(size_t)n * 128 + d] + b1v[dt];
      float pre[4];
      pre[0] = acc[dt][0] + t1v + (float)t2b[(size_t)gi.x * 128 + d];
      pre[1] = acc[dt][1] + t1v + (float)t2b[(size_t)gi.y * 128 + d];
      pre[2] = acc[dt][2] + t1v + (float)t2b[(size_t)gi.z * 128 + d];
      pre[3] = acc[dt][3] + t1v + (float)t2b[(size_t)gi.w * 128 + d];
      float s = 0.f;
      #pragma unroll
      for (int j = 0; j < 4; ++j) s += pre[j] / (1.0f + __expf(-pre[j]));
      s += __shfl_xor(s, 16, 64);
      s += __shfl_xor(s, 32, 64);
      ssum[dt] = s;
    }
    if (lane < 16) {
      #pragma unroll
      for (int dt = 0; dt < 8; ++dt)
        hsum[(size_t)n * 128 + dt * 16 + lane] = ssum[dt];
    }
  }
}

// ---------------------------------------------------------------------------
// K4: out = x + hsum @ W2 + 16*b2.  (unchanged, known-good)
// ---------------------------------------------------------------------------
__global__ __launch_bounds__(256) void k_out(const float* __restrict__ hsum,
                                             const float* __restrict__ W2,
                                             const float* __restrict__ b2,
                                             const float* __restrict__ x,
                                             float* __restrict__ out) {
  const int t = threadIdx.x;
  const int d = t & 127;
  int nb4 = blockIdx.x * 8 + (t >> 7) * 4;
  nb4 = __builtin_amdgcn_readfirstlane(nb4);
  float acc[4] = {0.0f, 0.0f, 0.0f, 0.0f};
  for (int k4 = 0; k4 < 32; ++k4) {
    const float w0  = W2[(size_t)(4 * k4 + 0) * 128 + d];
    const float w1v = W2[(size_t)(4 * k4 + 1) * 128 + d];
    const float w2v = W2[(size_t)(4 * k4 + 2) * 128 + d];
    const float w3v = W2[(size_t)(4 * k4 + 3) * 128 + d];
    #pragma unroll
    for (int i = 0; i < 4; ++i) {
      const float4 a = *(const float4*)(hsum + (size_t)(nb4 + i) * 128 + 4 * k4);
      acc[i] = fmaf(a.x, w0,  acc[i]);
      acc[i] = fmaf(a.y, w1v, acc[i]);
      acc[i] = fmaf(a.z, w2v, acc[i]);
      acc[i] = fmaf(a.w, w3v, acc[i]);
    }
  }
  const float b2v = 16.0f * b2[d];
  #pragma unroll
  for (int i = 0; i < 4; ++i) {
    const size_t o = (size_t)(nb4 + i) * 128 + d;
    out[o] = x[o] + acc[i] + b2v;
  }
}

// ---------------------------------------------------------------------------
extern "C" void kernel_launch(void* const* d_in, const int* in_sizes, int n_in,
                              void* d_out, int out_size, void* d_ws, size_t ws_size,
                              hipStream_t stream) {
  const float* x        = (const float*)d_in[0];
  const float* nbr_fea  = (const float*)d_in[1];
  const int*   nbr_idx  = (const int*)d_in[2];
  const float* ln_scale = (const float*)d_in[3];
  const float* ln_bias  = (const float*)d_in[4];
  const float* W1       = (const float*)d_in[5];
  const float* b1       = (const float*)d_in[6];
  const float* W2       = (const float*)d_in[7];
  const float* b2       = (const float*)d_in[8];
  float* out = (float*)d_out;

  const size_t NF = (size_t)N_NODES * D;
  float*  xn   = (float*)d_ws;           // [N,128] f32
  float*  t1   = xn + NF;                // [N,128] f32
  __bf16* t2b  = (__bf16*)(t1 + NF);     // [N,128] bf16
  float*  hsum = xn;                     // reuse xn (dead after k_t12)

  k_ln  <<<N_NODES / 4,  256, 0, stream>>>(x, ln_scale, ln_bias, xn);
  k_t12 <<<N_NODES / 16, 256, 0, stream>>>(xn, W1, t1, t2b);
  k_edge<<<(N_NODES + 63) / 64, 256, 0, stream>>>(nbr_fea, nbr_idx, t1, t2b, W1, b1, hsum);
  k_out <<<N_NODES / 8,  256, 0, stream>>>(hsum, W2, b2, x, out);
}

// Round 5
// 259.924 us; speedup vs baseline: 2.0537x; 1.0862x over previous
//
#include <hip/hip_runtime.h>
#include <math.h>

#define N_NODES 50000
#define M_NBR 16
#define D 128
#define E 64

typedef __attribute__((ext_vector_type(8))) __bf16 bf16x8;
typedef __attribute__((ext_vector_type(4))) float f32x4;

// ---------------------------------------------------------------------------
// K1: LayerNorm.  One wave per row (4 rows / 256-thread block).
// ---------------------------------------------------------------------------
__global__ __launch_bounds__(256) void k_ln(const float* __restrict__ x,
                                            const float* __restrict__ sc,
                                            const float* __restrict__ bi,
                                            float* __restrict__ xn) {
  const int row  = blockIdx.x * 4 + (threadIdx.x >> 6);
  const int lane = threadIdx.x & 63;
  float2 v = ((const float2*)(x + (size_t)row * D))[lane];
  float s = v.x + v.y;
  #pragma unroll
  for (int o = 32; o; o >>= 1) s += __shfl_xor(s, o, 64);
  const float mu = s * (1.0f / 128.0f);
  const float dx = v.x - mu, dy = v.y - mu;
  float q = dx * dx + dy * dy;
  #pragma unroll
  for (int o = 32; o; o >>= 1) q += __shfl_xor(q, o, 64);
  const float r = rsqrtf(q * (1.0f / 128.0f) + 1e-6f);
  float2 o2;
  o2.x = fmaf(dx * r, sc[2 * lane],     bi[2 * lane]);
  o2.y = fmaf(dy * r, sc[2 * lane + 1], bi[2 * lane + 1]);
  ((float2*)(xn + (size_t)row * D))[lane] = o2;
}

// ---------------------------------------------------------------------------
// K2: t1 = xn @ W1[0:128] (fp32), t2b = bf16(xn @ W1[128:256]).
// ---------------------------------------------------------------------------
__global__ __launch_bounds__(256) void k_t12(const float* __restrict__ xn,
                                             const float* __restrict__ W1,
                                             float* __restrict__ t1,
                                             __bf16* __restrict__ t2b) {
  const int t  = threadIdx.x;
  const int n0 = blockIdx.x * 16;
  const float* wcol = W1 + (t < 128 ? t : (128 * 128 + (t - 128)));
  float acc[16];
  #pragma unroll
  for (int i = 0; i < 16; ++i) acc[i] = 0.0f;
  for (int k4 = 0; k4 < 32; ++k4) {
    const float w0  = wcol[(size_t)(4 * k4 + 0) * 128];
    const float w1v = wcol[(size_t)(4 * k4 + 1) * 128];
    const float w2v = wcol[(size_t)(4 * k4 + 2) * 128];
    const float w3v = wcol[(size_t)(4 * k4 + 3) * 128];
    #pragma unroll
    for (int i = 0; i < 16; ++i) {
      const float4 a = *(const float4*)(xn + (size_t)(n0 + i) * 128 + 4 * k4);
      acc[i] = fmaf(a.x, w0,  acc[i]);
      acc[i] = fmaf(a.y, w1v, acc[i]);
      acc[i] = fmaf(a.z, w2v, acc[i]);
      acc[i] = fmaf(a.w, w3v, acc[i]);
    }
  }
  if (t < 128) {
    #pragma unroll
    for (int i = 0; i < 16; ++i) t1[(size_t)(n0 + i) * 128 + t] = acc[i];
  } else {
    #pragma unroll
    for (int i = 0; i < 16; ++i)
      t2b[(size_t)(n0 + i) * 128 + (t - 128)] = (__bf16)acc[i];
  }
}

// ---------------------------------------------------------------------------
// K3: edge GEMM via bf16 MFMA + gather + silu + m-sum.
// R5 restructure: 4 nodes per wave (grid 3125, no tail); idx prefetched for
// all 4 nodes at wave start; per node, loads issue in phases (A first, then
// all 32 gathers + 8 t1 into arrays) so MFMAs run with gathers in flight and
// only ONE latency window per node is exposed.
// ---------------------------------------------------------------------------
__global__ __launch_bounds__(256) void k_edge(const float* __restrict__ nbr,
                                              const int* __restrict__ idx,
                                              const float* __restrict__ t1,
                                              const __bf16* __restrict__ t2b,
                                              const float* __restrict__ W1,
                                              const float* __restrict__ b1,
                                              float* __restrict__ hsum) {
  const int lane = threadIdx.x & 63;
  const int wid  = threadIdx.x >> 6;
  const int r    = lane & 15;   // A row (edge); D col (d) in epilogue
  const int c    = lane >> 4;   // k-chunk; D row-group in epilogue
  const float* W1c = W1 + 256 * 128;

  // B fragments for all 8 d-tiles x 2 k-steps (loaded once, L2-hot).
  bf16x8 bfrag[8][2];
  #pragma unroll
  for (int dt = 0; dt < 8; ++dt) {
    #pragma unroll
    for (int ko = 0; ko < 2; ++ko) {
      #pragma unroll
      for (int j = 0; j < 8; ++j) {
        const int k = ko * 32 + c * 8 + j;
        bfrag[dt][ko][j] = (__bf16)W1c[k * 128 + dt * 16 + r];
      }
    }
  }
  float b1v[8];
  #pragma unroll
  for (int dt = 0; dt < 8; ++dt) b1v[dt] = b1[dt * 16 + r];

  const int node0 = (blockIdx.x * 4 + wid) * 4;   // 4 nodes per wave

  // Prefetch idx for all 4 nodes (kills the idx->gather dependent hop).
  int4 gi[4];
  #pragma unroll
  for (int i = 0; i < 4; ++i)
    gi[i] = *(const int4*)(idx + (node0 + i) * M_NBR + c * 4);

  #pragma unroll 1
  for (int i = 0; i < 4; ++i) {
    const int n = node0 + i;

    // Phase 1: A loads (MFMA waits only on these).
    const float* arow = nbr + (size_t)n * (M_NBR * E) + r * E + c * 8;
    const float4 lo0 = *(const float4*)(arow);
    const float4 hi0 = *(const float4*)(arow + 4);
    const float4 lo1 = *(const float4*)(arow + 32);
    const float4 hi1 = *(const float4*)(arow + 36);

    // Phase 2: all gathers + t1 issued into arrays (in flight under MFMA).
    __bf16 tg[8][4];
    const int4 g = gi[i];
    #pragma unroll
    for (int dt = 0; dt < 8; ++dt) {
      const int d = dt * 16 + r;
      tg[dt][0] = t2b[(size_t)g.x * 128 + d];
      tg[dt][1] = t2b[(size_t)g.y * 128 + d];
      tg[dt][2] = t2b[(size_t)g.z * 128 + d];
      tg[dt][3] = t2b[(size_t)g.w * 128 + d];
    }
    float t1v[8];
    #pragma unroll
    for (int dt = 0; dt < 8; ++dt) t1v[dt] = t1[(size_t)n * 128 + dt * 16 + r];

    // Phase 3: MFMAs (A only).
    bf16x8 af0, af1;
    af0[0] = (__bf16)lo0.x; af0[1] = (__bf16)lo0.y;
    af0[2] = (__bf16)lo0.z; af0[3] = (__bf16)lo0.w;
    af0[4] = (__bf16)hi0.x; af0[5] = (__bf16)hi0.y;
    af0[6] = (__bf16)hi0.z; af0[7] = (__bf16)hi0.w;
    af1[0] = (__bf16)lo1.x; af1[1] = (__bf16)lo1.y;
    af1[2] = (__bf16)lo1.z; af1[3] = (__bf16)lo1.w;
    af1[4] = (__bf16)hi1.x; af1[5] = (__bf16)hi1.y;
    af1[6] = (__bf16)hi1.z; af1[7] = (__bf16)hi1.w;

    f32x4 acc[8];
    #pragma unroll
    for (int dt = 0; dt < 8; ++dt) acc[dt] = (f32x4){0.f, 0.f, 0.f, 0.f};
    #pragma unroll
    for (int dt = 0; dt < 8; ++dt) {
      acc[dt] = __builtin_amdgcn_mfma_f32_16x16x32_bf16(af0, bfrag[dt][0], acc[dt], 0, 0, 0);
      acc[dt] = __builtin_amdgcn_mfma_f32_16x16x32_bf16(af1, bfrag[dt][1], acc[dt], 0, 0, 0);
    }

    // Phase 4: single wait, silu, m-reduce, store.
    float ssum[8];
    #pragma unroll
    for (int dt = 0; dt < 8; ++dt) {
      const float tb = t1v[dt] + b1v[dt];
      float s = 0.f;
      #pragma unroll
      for (int j = 0; j < 4; ++j) {
        const float h = acc[dt][j] + tb + (float)tg[dt][j];
        s += h * __frcp_rn(1.0f + __expf(-h));
      }
      s += __shfl_xor(s, 16, 64);
      s += __shfl_xor(s, 32, 64);
      ssum[dt] = s;
    }
    if (lane < 16) {
      #pragma unroll
      for (int dt = 0; dt < 8; ++dt)
        hsum[(size_t)n * 128 + dt * 16 + lane] = ssum[dt];
    }
  }
}

// ---------------------------------------------------------------------------
// K4: out = x + hsum @ W2 + 16*b2.  (unchanged, known-good)
// ---------------------------------------------------------------------------
__global__ __launch_bounds__(256) void k_out(const float* __restrict__ hsum,
                                             const float* __restrict__ W2,
                                             const float* __restrict__ b2,
                                             const float* __restrict__ x,
                                             float* __restrict__ out) {
  const int t = threadIdx.x;
  const int d = t & 127;
  int nb4 = blockIdx.x * 8 + (t >> 7) * 4;
  nb4 = __builtin_amdgcn_readfirstlane(nb4);
  float acc[4] = {0.0f, 0.0f, 0.0f, 0.0f};
  for (int k4 = 0; k4 < 32; ++k4) {
    const float w0  = W2[(size_t)(4 * k4 + 0) * 128 + d];
    const float w1v = W2[(size_t)(4 * k4 + 1) * 128 + d];
    const float w2v = W2[(size_t)(4 * k4 + 2) * 128 + d];
    const float w3v = W2[(size_t)(4 * k4 + 3) * 128 + d];
    #pragma unroll
    for (int i = 0; i < 4; ++i) {
      const float4 a = *(const float4*)(hsum + (size_t)(nb4 + i) * 128 + 4 * k4);
      acc[i] = fmaf(a.x, w0,  acc[i]);
      acc[i] = fmaf(a.y, w1v, acc[i]);
      acc[i] = fmaf(a.z, w2v, acc[i]);
      acc[i] = fmaf(a.w, w3v, acc[i]);
    }
  }
  const float b2v = 16.0f * b2[d];
  #pragma unroll
  for (int i = 0; i < 4; ++i) {
    const size_t o = (size_t)(nb4 + i) * 128 + d;
    out[o] = x[o] + acc[i] + b2v;
  }
}

// ---------------------------------------------------------------------------
extern "C" void kernel_launch(void* const* d_in, const int* in_sizes, int n_in,
                              void* d_out, int out_size, void* d_ws, size_t ws_size,
                              hipStream_t stream) {
  const float* x        = (const float*)d_in[0];
  const float* nbr_fea  = (const float*)d_in[1];
  const int*   nbr_idx  = (const int*)d_in[2];
  const float* ln_scale = (const float*)d_in[3];
  const float* ln_bias  = (const float*)d_in[4];
  const float* W1       = (const float*)d_in[5];
  const float* b1       = (const float*)d_in[6];
  const float* W2       = (const float*)d_in[7];
  const float* b2       = (const float*)d_in[8];
  float* out = (float*)d_out;

  const size_t NF = (size_t)N_NODES * D;
  float*  xn   = (float*)d_ws;           // [N,128] f32
  float*  t1   = xn + NF;                // [N,128] f32
  __bf16* t2b  = (__bf16*)(t1 + NF);     // [N,128] bf16
  float*  hsum = xn;                     // reuse xn (dead after k_t12)

  k_ln  <<<N_NODES / 4,  256, 0, stream>>>(x, ln_scale, ln_bias, xn);
  k_t12 <<<N_NODES / 16, 256, 0, stream>>>(xn, W1, t1, t2b);
  k_edge<<<N_NODES / 16, 256, 0, stream>>>(nbr_fea, nbr_idx, t1, t2b, W1, b1, hsum);
  k_out <<<N_NODES / 8,  256, 0, stream>>>(hsum, W2, b2, x, out);
}

// Round 6
// 158.376 us; speedup vs baseline: 3.3705x; 1.6412x over previous
//
#include <hip/hip_runtime.h>
#include <math.h>

#define N_NODES 50000
#define M_NBR 16
#define D 128
#define E 64

typedef __attribute__((ext_vector_type(8))) __bf16 bf16x8;
typedef __attribute__((ext_vector_type(4))) float f32x4;

// Fragment-permuted weight storage (bf16):
//   flat = (((dt*NKT + kt)*4 + c)*16 + r)*8 + j
// holds W_natural[k = kt*32 + c*8 + j][d = dt*16 + r].
// Lane (r,c) then loads one bf16x8 at vector-index (dt*NKT+kt)*64 + c*16 + r.

// ---------------------------------------------------------------------------
// K0: build fragment-permuted bf16 weights.
//   region 0: W1a (rows   0..127 of W1), NKT=4, 16384 elems
//   region 1: W1b (rows 128..255),       NKT=4, 16384
//   region 2: W1c (rows 256..319),       NKT=2,  8192
//   region 3: W2 with k remapped: stored-k i -> natural k (i&7)*16+(i>>3)
// ---------------------------------------------------------------------------
__global__ __launch_bounds__(256) void k_prep(const float* __restrict__ W1,
                                              const float* __restrict__ W2,
                                              __bf16* __restrict__ w1a_f,
                                              __bf16* __restrict__ w1b_f,
                                              __bf16* __restrict__ w1c_f,
                                              __bf16* __restrict__ w2_f) {
  const int t = blockIdx.x * 256 + threadIdx.x;
  if (t < 16384) {                       // W1a
    const int j = t & 7, r = (t >> 3) & 15, c = (t >> 7) & 3, q = t >> 9;
    const int kt = q & 3, dt = q >> 2;
    w1a_f[t] = (__bf16)W1[(kt * 32 + c * 8 + j) * 128 + dt * 16 + r];
  } else if (t < 32768) {                // W1b
    const int u = t - 16384;
    const int j = u & 7, r = (u >> 3) & 15, c = (u >> 7) & 3, q = u >> 9;
    const int kt = q & 3, dt = q >> 2;
    w1b_f[u] = (__bf16)W1[(128 + kt * 32 + c * 8 + j) * 128 + dt * 16 + r];
  } else if (t < 40960) {                // W1c (NKT=2)
    const int u = t - 32768;
    const int j = u & 7, r = (u >> 3) & 15, c = (u >> 7) & 3, q = u >> 9;
    const int kt = q & 1, dt = q >> 1;
    w1c_f[u] = (__bf16)W1[(256 + kt * 32 + c * 8 + j) * 128 + dt * 16 + r];
  } else if (t < 57344) {                // W2, permuted k
    const int u = t - 40960;
    const int j = u & 7, r = (u >> 3) & 15, c = (u >> 7) & 3, q = u >> 9;
    const int kt = q & 3, dt = q >> 2;
    const int i = kt * 32 + c * 8 + j;             // stored-k
    const int ak = (i & 7) * 16 + (i >> 3);        // natural k in hsum row
    w2_f[u] = (__bf16)W2[ak * 128 + dt * 16 + r];
  }
}

// ---------------------------------------------------------------------------
// K1: fused LayerNorm + dual GEMM via MFMA.
// Wave = 16 nodes. Lane (r,c): A row = node r, k = kt*32 + c*8 + j.
// LN in-reg: lane-local 32-elem sums + shfl_xor(16,32) across c-groups.
// Outputs (permuted [n][r*8+dt]): t1p = xn@W1a + b1 (f32), t2bp = xn@W1b (bf16).
// ---------------------------------------------------------------------------
__global__ __launch_bounds__(256) void k_t12f(const float* __restrict__ x,
                                              const float* __restrict__ sc,
                                              const float* __restrict__ bi,
                                              const __bf16* __restrict__ w1a_f,
                                              const __bf16* __restrict__ w1b_f,
                                              const float* __restrict__ b1,
                                              float* __restrict__ t1p,
                                              __bf16* __restrict__ t2bp) {
  const int wave = blockIdx.x * 4 + (threadIdx.x >> 6);
  if (wave >= N_NODES / 16) return;
  const int lane = threadIdx.x & 63;
  const int r = lane & 15, c = lane >> 4;
  const int node0 = wave * 16;

  // ---- load this lane's 32 row elements (node0+r, k = kt*32+c*8 ..+8)
  const float* row = x + (size_t)(node0 + r) * 128 + c * 8;
  f32x4 va[8];
  #pragma unroll
  for (int kt = 0; kt < 4; ++kt) {
    va[2 * kt]     = *(const f32x4*)(row + kt * 32);
    va[2 * kt + 1] = *(const f32x4*)(row + kt * 32 + 4);
  }
  // ---- LN statistics
  float s = 0.f;
  #pragma unroll
  for (int q = 0; q < 8; ++q) s += va[q][0] + va[q][1] + va[q][2] + va[q][3];
  s += __shfl_xor(s, 16, 64);
  s += __shfl_xor(s, 32, 64);
  const float mu = s * (1.0f / 128.0f);
  float qs = 0.f;
  #pragma unroll
  for (int q = 0; q < 8; ++q) {
    #pragma unroll
    for (int e = 0; e < 4; ++e) { const float dxx = va[q][e] - mu; qs += dxx * dxx; }
  }
  qs += __shfl_xor(qs, 16, 64);
  qs += __shfl_xor(qs, 32, 64);
  const float rs = rsqrtf(qs * (1.0f / 128.0f) + 1e-6f);

  // ---- normalize + scale/bias + cvt -> A fragments
  bf16x8 af[4];
  #pragma unroll
  for (int kt = 0; kt < 4; ++kt) {
    const f32x4 s_lo = *(const f32x4*)(sc + kt * 32 + c * 8);
    const f32x4 s_hi = *(const f32x4*)(sc + kt * 32 + c * 8 + 4);
    const f32x4 b_lo = *(const f32x4*)(bi + kt * 32 + c * 8);
    const f32x4 b_hi = *(const f32x4*)(bi + kt * 32 + c * 8 + 4);
    #pragma unroll
    for (int e = 0; e < 4; ++e) {
      af[kt][e]     = (__bf16)(((va[2 * kt][e]     - mu) * rs) * s_lo[e] + b_lo[e]);
      af[kt][4 + e] = (__bf16)(((va[2 * kt + 1][e] - mu) * rs) * s_hi[e] + b_hi[e]);
    }
  }

  // ---- dual GEMM
  const bf16x8* wa = (const bf16x8*)w1a_f;
  const bf16x8* wb = (const bf16x8*)w1b_f;
  f32x4 acc1[8], acc2[8];
  #pragma unroll
  for (int dt = 0; dt < 8; ++dt) { acc1[dt] = (f32x4){0,0,0,0}; acc2[dt] = (f32x4){0,0,0,0}; }
  #pragma unroll
  for (int dt = 0; dt < 8; ++dt) {
    #pragma unroll
    for (int kt = 0; kt < 4; ++kt) {
      const bf16x8 bfa = wa[(dt * 4 + kt) * 64 + c * 16 + r];
      acc1[dt] = __builtin_amdgcn_mfma_f32_16x16x32_bf16(af[kt], bfa, acc1[dt], 0, 0, 0);
      const bf16x8 bfb = wb[(dt * 4 + kt) * 64 + c * 16 + r];
      acc2[dt] = __builtin_amdgcn_mfma_f32_16x16x32_bf16(af[kt], bfb, acc2[dt], 0, 0, 0);
    }
  }

  // ---- epilogue: D row = node c*4+j, col = dt*16+r.  Store permuted rows.
  float b1v[8];
  #pragma unroll
  for (int dt = 0; dt < 8; ++dt) b1v[dt] = b1[dt * 16 + r];
  #pragma unroll
  for (int j = 0; j < 4; ++j) {
    const int node = node0 + c * 4 + j;
    f32x4 t1lo, t1hi;
    bf16x8 t2v;
    #pragma unroll
    for (int dt = 0; dt < 4; ++dt)  t1lo[dt]     = acc1[dt][j] + b1v[dt];
    #pragma unroll
    for (int dt = 4; dt < 8; ++dt)  t1hi[dt - 4] = acc1[dt][j] + b1v[dt];
    #pragma unroll
    for (int dt = 0; dt < 8; ++dt)  t2v[dt] = (__bf16)acc2[dt][j];
    *(f32x4*)(t1p + (size_t)node * 128 + r * 8)     = t1lo;
    *(f32x4*)(t1p + (size_t)node * 128 + r * 8 + 4) = t1hi;
    *(bf16x8*)(t2bp + (size_t)node * 128 + r * 8)   = t2v;
  }
}

// ---------------------------------------------------------------------------
// K2: edge GEMM via bf16 MFMA + 16B-gather + silu + m-sum.
// 4 nodes per wave.  bfrag from fragment-permuted W1c (16 x 16B loads).
// t2 gather: ONE bf16x8 (16B) load per edge (named vars -> no LDS promotion).
// t1p already includes b1.  hsum stored permuted [n][r*8+dt].
// ---------------------------------------------------------------------------
__global__ __launch_bounds__(256) void k_edge(const float* __restrict__ nbr,
                                              const int* __restrict__ idx,
                                              const float* __restrict__ t1p,
                                              const __bf16* __restrict__ t2bp,
                                              const __bf16* __restrict__ w1c_f,
                                              float* __restrict__ hsum_p) {
  const int lane = threadIdx.x & 63;
  const int wid  = threadIdx.x >> 6;
  const int r = lane & 15, c = lane >> 4;

  const bf16x8* wc = (const bf16x8*)w1c_f;
  bf16x8 bfrag[8][2];
  #pragma unroll
  for (int dt = 0; dt < 8; ++dt) {
    bfrag[dt][0] = wc[(dt * 2 + 0) * 64 + c * 16 + r];
    bfrag[dt][1] = wc[(dt * 2 + 1) * 64 + c * 16 + r];
  }

  const int node0 = (blockIdx.x * 4 + wid) * 4;
  int4 gi[4];
  #pragma unroll
  for (int i = 0; i < 4; ++i)
    gi[i] = *(const int4*)(idx + (node0 + i) * M_NBR + c * 4);

  #pragma unroll 1
  for (int i = 0; i < 4; ++i) {
    const int n = node0 + i;

    // A loads (MFMA waits only on these)
    const float* arow = nbr + (size_t)n * (M_NBR * E) + r * E + c * 8;
    const f32x4 lo0 = *(const f32x4*)(arow);
    const f32x4 hi0 = *(const f32x4*)(arow + 4);
    const f32x4 lo1 = *(const f32x4*)(arow + 32);
    const f32x4 hi1 = *(const f32x4*)(arow + 36);

    // gathers + t1p issued now, consumed after MFMAs
    const int4 g = gi[i];
    const bf16x8 tg0 = *(const bf16x8*)(t2bp + (size_t)g.x * 128 + r * 8);
    const bf16x8 tg1 = *(const bf16x8*)(t2bp + (size_t)g.y * 128 + r * 8);
    const bf16x8 tg2 = *(const bf16x8*)(t2bp + (size_t)g.z * 128 + r * 8);
    const bf16x8 tg3 = *(const bf16x8*)(t2bp + (size_t)g.w * 128 + r * 8);
    const f32x4 t1lo = *(const f32x4*)(t1p + (size_t)n * 128 + r * 8);
    const f32x4 t1hi = *(const f32x4*)(t1p + (size_t)n * 128 + r * 8 + 4);

    bf16x8 af0, af1;
    #pragma unroll
    for (int e = 0; e < 4; ++e) {
      af0[e] = (__bf16)lo0[e]; af0[4 + e] = (__bf16)hi0[e];
      af1[e] = (__bf16)lo1[e]; af1[4 + e] = (__bf16)hi1[e];
    }

    f32x4 acc[8];
    #pragma unroll
    for (int dt = 0; dt < 8; ++dt) acc[dt] = (f32x4){0,0,0,0};
    #pragma unroll
    for (int dt = 0; dt < 8; ++dt) {
      acc[dt] = __builtin_amdgcn_mfma_f32_16x16x32_bf16(af0, bfrag[dt][0], acc[dt], 0, 0, 0);
      acc[dt] = __builtin_amdgcn_mfma_f32_16x16x32_bf16(af1, bfrag[dt][1], acc[dt], 0, 0, 0);
    }

    // epilogue: h = acc + t1p(+b1) + t2[g];  silu; reduce over c-groups.
    float ssum[8];
    #pragma unroll
    for (int dt = 0; dt < 8; ++dt) {
      const float tb = (dt < 4) ? t1lo[dt & 3] : t1hi[dt & 3];
      float s = 0.f;
      {
        const float h = acc[dt][0] + tb + (float)tg0[dt];
        s += h / (1.0f + __expf(-h));
      }
      {
        const float h = acc[dt][1] + tb + (float)tg1[dt];
        s += h / (1.0f + __expf(-h));
      }
      {
        const float h = acc[dt][2] + tb + (float)tg2[dt];
        s += h / (1.0f + __expf(-h));
      }
      {
        const float h = acc[dt][3] + tb + (float)tg3[dt];
        s += h / (1.0f + __expf(-h));
      }
      s += __shfl_xor(s, 16, 64);
      s += __shfl_xor(s, 32, 64);
      ssum[dt] = s;
    }
    if (lane < 16) {
      f32x4 o_lo, o_hi;
      #pragma unroll
      for (int dt = 0; dt < 4; ++dt) { o_lo[dt] = ssum[dt]; o_hi[dt] = ssum[dt + 4]; }
      *(f32x4*)(hsum_p + (size_t)n * 128 + r * 8)     = o_lo;
      *(f32x4*)(hsum_p + (size_t)n * 128 + r * 8 + 4) = o_hi;
    }
  }
}

// ---------------------------------------------------------------------------
// K3: out = x + hsum@W2 + 16*b2 via MFMA.  Wave = 16 nodes.
// A = permuted hsum rows (stored-k order); B = w2_f (k remapped to match).
// ---------------------------------------------------------------------------
__global__ __launch_bounds__(256) void k_out(const float* __restrict__ hsum_p,
                                             const __bf16* __restrict__ w2_f,
                                             const float* __restrict__ b2,
                                             const float* __restrict__ x,
                                             float* __restrict__ out) {
  const int wave = blockIdx.x * 4 + (threadIdx.x >> 6);
  if (wave >= N_NODES / 16) return;
  const int lane = threadIdx.x & 63;
  const int r = lane & 15, c = lane >> 4;
  const int node0 = wave * 16;

  // A fragments from permuted hsum row (stored-k = kt*32+c*8+j)
  const float* row = hsum_p + (size_t)(node0 + r) * 128 + c * 8;
  bf16x8 af[4];
  #pragma unroll
  for (int kt = 0; kt < 4; ++kt) {
    const f32x4 lo = *(const f32x4*)(row + kt * 32);
    const f32x4 hi = *(const f32x4*)(row + kt * 32 + 4);
    #pragma unroll
    for (int e = 0; e < 4; ++e) { af[kt][e] = (__bf16)lo[e]; af[kt][4 + e] = (__bf16)hi[e]; }
  }

  const bf16x8* w2 = (const bf16x8*)w2_f;
  f32x4 acc[8];
  #pragma unroll
  for (int dt = 0; dt < 8; ++dt) acc[dt] = (f32x4){0,0,0,0};
  #pragma unroll
  for (int dt = 0; dt < 8; ++dt) {
    #pragma unroll
    for (int kt = 0; kt < 4; ++kt) {
      const bf16x8 bf = w2[(dt * 4 + kt) * 64 + c * 16 + r];
      acc[dt] = __builtin_amdgcn_mfma_f32_16x16x32_bf16(af[kt], bf, acc[dt], 0, 0, 0);
    }
  }

  float b2v[8];
  #pragma unroll
  for (int dt = 0; dt < 8; ++dt) b2v[dt] = 16.0f * b2[dt * 16 + r];
  #pragma unroll
  for (int j = 0; j < 4; ++j) {
    const int node = node0 + c * 4 + j;
    #pragma unroll
    for (int dt = 0; dt < 8; ++dt) {
      const size_t o = (size_t)node * 128 + dt * 16 + r;
      out[o] = x[o] + acc[dt][j] + b2v[dt];
    }
  }
}

// ---------------------------------------------------------------------------
extern "C" void kernel_launch(void* const* d_in, const int* in_sizes, int n_in,
                              void* d_out, int out_size, void* d_ws, size_t ws_size,
                              hipStream_t stream) {
  const float* x        = (const float*)d_in[0];
  const float* nbr_fea  = (const float*)d_in[1];
  const int*   nbr_idx  = (const int*)d_in[2];
  const float* ln_scale = (const float*)d_in[3];
  const float* ln_bias  = (const float*)d_in[4];
  const float* W1       = (const float*)d_in[5];
  const float* b1       = (const float*)d_in[6];
  const float* W2       = (const float*)d_in[7];
  const float* b2       = (const float*)d_in[8];
  float* out = (float*)d_out;

  char* ws = (char*)d_ws;
  float*  t1p    = (float*)(ws);                       // 25,600,000 B
  float*  hsum_p = (float*)(ws + 25600000);            // 25,600,000 B
  __bf16* t2bp   = (__bf16*)(ws + 51200000);           // 12,800,000 B
  __bf16* w1a_f  = (__bf16*)(ws + 64000000);           //     32,768 B
  __bf16* w1b_f  = (__bf16*)(ws + 64032768);           //     32,768 B
  __bf16* w1c_f  = (__bf16*)(ws + 64065536);           //     16,384 B
  __bf16* w2_f   = (__bf16*)(ws + 64081920);           //     32,768 B

  k_prep <<<224, 256, 0, stream>>>(W1, W2, w1a_f, w1b_f, w1c_f, w2_f);
  k_t12f <<<(N_NODES / 16 + 3) / 4, 256, 0, stream>>>(x, ln_scale, ln_bias,
                                                      w1a_f, w1b_f, b1, t1p, t2bp);
  k_edge <<<N_NODES / 16, 256, 0, stream>>>(nbr_fea, nbr_idx, t1p, t2bp, w1c_f, hsum_p);
  k_out  <<<(N_NODES / 16 + 3) / 4, 256, 0, stream>>>(hsum_p, w2_f, b2, x, out);
}

// Round 7
// 153.611 us; speedup vs baseline: 3.4751x; 1.0310x over previous
//
#include <hip/hip_runtime.h>
#include <math.h>

#define N_NODES 50000
#define M_NBR 16
#define D 128
#define E 64

typedef __attribute__((ext_vector_type(8))) __bf16 bf16x8;
typedef __attribute__((ext_vector_type(4))) float f32x4;

// Fragment-permuted weight storage (bf16):
//   flat = (((dt*NKT + kt)*4 + c)*16 + r)*8 + j
// holds W_natural[k = kt*32 + c*8 + j][d = dt*16 + r].
// Lane (r,c) then loads one bf16x8 at vector-index (dt*NKT+kt)*64 + c*16 + r.

// ---------------------------------------------------------------------------
// K0: build fragment-permuted bf16 weights.
// ---------------------------------------------------------------------------
__global__ __launch_bounds__(256) void k_prep(const float* __restrict__ W1,
                                              const float* __restrict__ W2,
                                              __bf16* __restrict__ w1a_f,
                                              __bf16* __restrict__ w1b_f,
                                              __bf16* __restrict__ w1c_f,
                                              __bf16* __restrict__ w2_f) {
  const int t = blockIdx.x * 256 + threadIdx.x;
  if (t < 16384) {                       // W1a
    const int j = t & 7, r = (t >> 3) & 15, c = (t >> 7) & 3, q = t >> 9;
    const int kt = q & 3, dt = q >> 2;
    w1a_f[t] = (__bf16)W1[(kt * 32 + c * 8 + j) * 128 + dt * 16 + r];
  } else if (t < 32768) {                // W1b
    const int u = t - 16384;
    const int j = u & 7, r = (u >> 3) & 15, c = (u >> 7) & 3, q = u >> 9;
    const int kt = q & 3, dt = q >> 2;
    w1b_f[u] = (__bf16)W1[(128 + kt * 32 + c * 8 + j) * 128 + dt * 16 + r];
  } else if (t < 40960) {                // W1c (NKT=2)
    const int u = t - 32768;
    const int j = u & 7, r = (u >> 3) & 15, c = (u >> 7) & 3, q = u >> 9;
    const int kt = q & 1, dt = q >> 1;
    w1c_f[u] = (__bf16)W1[(256 + kt * 32 + c * 8 + j) * 128 + dt * 16 + r];
  } else if (t < 57344) {                // W2, permuted k
    const int u = t - 40960;
    const int j = u & 7, r = (u >> 3) & 15, c = (u >> 7) & 3, q = u >> 9;
    const int kt = q & 3, dt = q >> 2;
    const int i = kt * 32 + c * 8 + j;             // stored-k
    const int ak = (i & 7) * 16 + (i >> 3);        // natural k in hsum row
    w2_f[u] = (__bf16)W2[ak * 128 + dt * 16 + r];
  }
}

// ---------------------------------------------------------------------------
// K1: fused LayerNorm + dual GEMM via MFMA.  (unchanged, known-good)
// ---------------------------------------------------------------------------
__global__ __launch_bounds__(256) void k_t12f(const float* __restrict__ x,
                                              const float* __restrict__ sc,
                                              const float* __restrict__ bi,
                                              const __bf16* __restrict__ w1a_f,
                                              const __bf16* __restrict__ w1b_f,
                                              const float* __restrict__ b1,
                                              float* __restrict__ t1p,
                                              __bf16* __restrict__ t2bp) {
  const int wave = blockIdx.x * 4 + (threadIdx.x >> 6);
  if (wave >= N_NODES / 16) return;
  const int lane = threadIdx.x & 63;
  const int r = lane & 15, c = lane >> 4;
  const int node0 = wave * 16;

  const float* row = x + (size_t)(node0 + r) * 128 + c * 8;
  f32x4 va[8];
  #pragma unroll
  for (int kt = 0; kt < 4; ++kt) {
    va[2 * kt]     = *(const f32x4*)(row + kt * 32);
    va[2 * kt + 1] = *(const f32x4*)(row + kt * 32 + 4);
  }
  float s = 0.f;
  #pragma unroll
  for (int q = 0; q < 8; ++q) s += va[q][0] + va[q][1] + va[q][2] + va[q][3];
  s += __shfl_xor(s, 16, 64);
  s += __shfl_xor(s, 32, 64);
  const float mu = s * (1.0f / 128.0f);
  float qs = 0.f;
  #pragma unroll
  for (int q = 0; q < 8; ++q) {
    #pragma unroll
    for (int e = 0; e < 4; ++e) { const float dxx = va[q][e] - mu; qs += dxx * dxx; }
  }
  qs += __shfl_xor(qs, 16, 64);
  qs += __shfl_xor(qs, 32, 64);
  const float rs = rsqrtf(qs * (1.0f / 128.0f) + 1e-6f);

  bf16x8 af[4];
  #pragma unroll
  for (int kt = 0; kt < 4; ++kt) {
    const f32x4 s_lo = *(const f32x4*)(sc + kt * 32 + c * 8);
    const f32x4 s_hi = *(const f32x4*)(sc + kt * 32 + c * 8 + 4);
    const f32x4 b_lo = *(const f32x4*)(bi + kt * 32 + c * 8);
    const f32x4 b_hi = *(const f32x4*)(bi + kt * 32 + c * 8 + 4);
    #pragma unroll
    for (int e = 0; e < 4; ++e) {
      af[kt][e]     = (__bf16)(((va[2 * kt][e]     - mu) * rs) * s_lo[e] + b_lo[e]);
      af[kt][4 + e] = (__bf16)(((va[2 * kt + 1][e] - mu) * rs) * s_hi[e] + b_hi[e]);
    }
  }

  const bf16x8* wa = (const bf16x8*)w1a_f;
  const bf16x8* wb = (const bf16x8*)w1b_f;
  f32x4 acc1[8], acc2[8];
  #pragma unroll
  for (int dt = 0; dt < 8; ++dt) { acc1[dt] = (f32x4){0,0,0,0}; acc2[dt] = (f32x4){0,0,0,0}; }
  #pragma unroll
  for (int dt = 0; dt < 8; ++dt) {
    #pragma unroll
    for (int kt = 0; kt < 4; ++kt) {
      const bf16x8 bfa = wa[(dt * 4 + kt) * 64 + c * 16 + r];
      acc1[dt] = __builtin_amdgcn_mfma_f32_16x16x32_bf16(af[kt], bfa, acc1[dt], 0, 0, 0);
      const bf16x8 bfb = wb[(dt * 4 + kt) * 64 + c * 16 + r];
      acc2[dt] = __builtin_amdgcn_mfma_f32_16x16x32_bf16(af[kt], bfb, acc2[dt], 0, 0, 0);
    }
  }

  float b1v[8];
  #pragma unroll
  for (int dt = 0; dt < 8; ++dt) b1v[dt] = b1[dt * 16 + r];
  #pragma unroll
  for (int j = 0; j < 4; ++j) {
    const int node = node0 + c * 4 + j;
    f32x4 t1lo, t1hi;
    bf16x8 t2v;
    #pragma unroll
    for (int dt = 0; dt < 4; ++dt)  t1lo[dt]     = acc1[dt][j] + b1v[dt];
    #pragma unroll
    for (int dt = 4; dt < 8; ++dt)  t1hi[dt - 4] = acc1[dt][j] + b1v[dt];
    #pragma unroll
    for (int dt = 0; dt < 8; ++dt)  t2v[dt] = (__bf16)acc2[dt][j];
    *(f32x4*)(t1p + (size_t)node * 128 + r * 8)     = t1lo;
    *(f32x4*)(t1p + (size_t)node * 128 + r * 8 + 4) = t1hi;
    *(bf16x8*)(t2bp + (size_t)node * 128 + r * 8)   = t2v;
  }
}

// ---------------------------------------------------------------------------
// K2: edge GEMM via bf16 MFMA + 16B-gather + silu + m-sum.
// R7: node loop FULLY UNROLLED (gi[i] etc. become static-indexed -> registers,
// kills the 16KB LDS demotion + 1.8M bank conflicts; lets the scheduler
// software-pipeline node i+1 loads under node i MFMA/epilogue).
// ---------------------------------------------------------------------------
__global__ __launch_bounds__(256) void k_edge(const float* __restrict__ nbr,
                                              const int* __restrict__ idx,
                                              const float* __restrict__ t1p,
                                              const __bf16* __restrict__ t2bp,
                                              const __bf16* __restrict__ w1c_f,
                                              float* __restrict__ hsum_p) {
  const int lane = threadIdx.x & 63;
  const int wid  = threadIdx.x >> 6;
  const int r = lane & 15, c = lane >> 4;

  const bf16x8* wc = (const bf16x8*)w1c_f;
  bf16x8 bfrag[8][2];
  #pragma unroll
  for (int dt = 0; dt < 8; ++dt) {
    bfrag[dt][0] = wc[(dt * 2 + 0) * 64 + c * 16 + r];
    bfrag[dt][1] = wc[(dt * 2 + 1) * 64 + c * 16 + r];
  }

  const int node0 = (blockIdx.x * 4 + wid) * 4;
  int4 gi[4];
  #pragma unroll
  for (int i = 0; i < 4; ++i)
    gi[i] = *(const int4*)(idx + (node0 + i) * M_NBR + c * 4);

  #pragma unroll
  for (int i = 0; i < 4; ++i) {
    const int n = node0 + i;

    // A loads (MFMA waits only on these)
    const float* arow = nbr + (size_t)n * (M_NBR * E) + r * E + c * 8;
    const f32x4 lo0 = *(const f32x4*)(arow);
    const f32x4 hi0 = *(const f32x4*)(arow + 4);
    const f32x4 lo1 = *(const f32x4*)(arow + 32);
    const f32x4 hi1 = *(const f32x4*)(arow + 36);

    // gathers + t1p issued now, consumed after MFMAs
    const int4 g = gi[i];
    const bf16x8 tg0 = *(const bf16x8*)(t2bp + (size_t)g.x * 128 + r * 8);
    const bf16x8 tg1 = *(const bf16x8*)(t2bp + (size_t)g.y * 128 + r * 8);
    const bf16x8 tg2 = *(const bf16x8*)(t2bp + (size_t)g.z * 128 + r * 8);
    const bf16x8 tg3 = *(const bf16x8*)(t2bp + (size_t)g.w * 128 + r * 8);
    const f32x4 t1lo = *(const f32x4*)(t1p + (size_t)n * 128 + r * 8);
    const f32x4 t1hi = *(const f32x4*)(t1p + (size_t)n * 128 + r * 8 + 4);

    bf16x8 af0, af1;
    #pragma unroll
    for (int e = 0; e < 4; ++e) {
      af0[e] = (__bf16)lo0[e]; af0[4 + e] = (__bf16)hi0[e];
      af1[e] = (__bf16)lo1[e]; af1[4 + e] = (__bf16)hi1[e];
    }

    f32x4 acc[8];
    #pragma unroll
    for (int dt = 0; dt < 8; ++dt) acc[dt] = (f32x4){0,0,0,0};
    #pragma unroll
    for (int dt = 0; dt < 8; ++dt) {
      acc[dt] = __builtin_amdgcn_mfma_f32_16x16x32_bf16(af0, bfrag[dt][0], acc[dt], 0, 0, 0);
      acc[dt] = __builtin_amdgcn_mfma_f32_16x16x32_bf16(af1, bfrag[dt][1], acc[dt], 0, 0, 0);
    }

    // epilogue: h = acc + t1p(+b1) + t2[g];  silu; reduce over c-groups.
    float ssum[8];
    #pragma unroll
    for (int dt = 0; dt < 8; ++dt) {
      const float tb = (dt < 4) ? t1lo[dt & 3] : t1hi[dt & 3];
      float s = 0.f;
      {
        const float h = acc[dt][0] + tb + (float)tg0[dt];
        s += h / (1.0f + __expf(-h));
      }
      {
        const float h = acc[dt][1] + tb + (float)tg1[dt];
        s += h / (1.0f + __expf(-h));
      }
      {
        const float h = acc[dt][2] + tb + (float)tg2[dt];
        s += h / (1.0f + __expf(-h));
      }
      {
        const float h = acc[dt][3] + tb + (float)tg3[dt];
        s += h / (1.0f + __expf(-h));
      }
      s += __shfl_xor(s, 16, 64);
      s += __shfl_xor(s, 32, 64);
      ssum[dt] = s;
    }
    if (lane < 16) {
      f32x4 o_lo, o_hi;
      #pragma unroll
      for (int dt = 0; dt < 4; ++dt) { o_lo[dt] = ssum[dt]; o_hi[dt] = ssum[dt + 4]; }
      *(f32x4*)(hsum_p + (size_t)n * 128 + r * 8)     = o_lo;
      *(f32x4*)(hsum_p + (size_t)n * 128 + r * 8 + 4) = o_hi;
    }
  }
}

// ---------------------------------------------------------------------------
// K3: out = x + hsum@W2 + 16*b2 via MFMA.  (unchanged, known-good)
// ---------------------------------------------------------------------------
__global__ __launch_bounds__(256) void k_out(const float* __restrict__ hsum_p,
                                             const __bf16* __restrict__ w2_f,
                                             const float* __restrict__ b2,
                                             const float* __restrict__ x,
                                             float* __restrict__ out) {
  const int wave = blockIdx.x * 4 + (threadIdx.x >> 6);
  if (wave >= N_NODES / 16) return;
  const int lane = threadIdx.x & 63;
  const int r = lane & 15, c = lane >> 4;
  const int node0 = wave * 16;

  const float* row = hsum_p + (size_t)(node0 + r) * 128 + c * 8;
  bf16x8 af[4];
  #pragma unroll
  for (int kt = 0; kt < 4; ++kt) {
    const f32x4 lo = *(const f32x4*)(row + kt * 32);
    const f32x4 hi = *(const f32x4*)(row + kt * 32 + 4);
    #pragma unroll
    for (int e = 0; e < 4; ++e) { af[kt][e] = (__bf16)lo[e]; af[kt][4 + e] = (__bf16)hi[e]; }
  }

  const bf16x8* w2 = (const bf16x8*)w2_f;
  f32x4 acc[8];
  #pragma unroll
  for (int dt = 0; dt < 8; ++dt) acc[dt] = (f32x4){0,0,0,0};
  #pragma unroll
  for (int dt = 0; dt < 8; ++dt) {
    #pragma unroll
    for (int kt = 0; kt < 4; ++kt) {
      const bf16x8 bf = w2[(dt * 4 + kt) * 64 + c * 16 + r];
      acc[dt] = __builtin_amdgcn_mfma_f32_16x16x32_bf16(af[kt], bf, acc[dt], 0, 0, 0);
    }
  }

  float b2v[8];
  #pragma unroll
  for (int dt = 0; dt < 8; ++dt) b2v[dt] = 16.0f * b2[dt * 16 + r];
  #pragma unroll
  for (int j = 0; j < 4; ++j) {
    const int node = node0 + c * 4 + j;
    #pragma unroll
    for (int dt = 0; dt < 8; ++dt) {
      const size_t o = (size_t)node * 128 + dt * 16 + r;
      out[o] = x[o] + acc[dt][j] + b2v[dt];
    }
  }
}

// ---------------------------------------------------------------------------
extern "C" void kernel_launch(void* const* d_in, const int* in_sizes, int n_in,
                              void* d_out, int out_size, void* d_ws, size_t ws_size,
                              hipStream_t stream) {
  const float* x        = (const float*)d_in[0];
  const float* nbr_fea  = (const float*)d_in[1];
  const int*   nbr_idx  = (const int*)d_in[2];
  const float* ln_scale = (const float*)d_in[3];
  const float* ln_bias  = (const float*)d_in[4];
  const float* W1       = (const float*)d_in[5];
  const float* b1       = (const float*)d_in[6];
  const float* W2       = (const float*)d_in[7];
  const float* b2       = (const float*)d_in[8];
  float* out = (float*)d_out;

  char* ws = (char*)d_ws;
  float*  t1p    = (float*)(ws);                       // 25,600,000 B
  float*  hsum_p = (float*)(ws + 25600000);            // 25,600,000 B
  __bf16* t2bp   = (__bf16*)(ws + 51200000);           // 12,800,000 B
  __bf16* w1a_f  = (__bf16*)(ws + 64000000);           //     32,768 B
  __bf16* w1b_f  = (__bf16*)(ws + 64032768);           //     32,768 B
  __bf16* w1c_f  = (__bf16*)(ws + 64065536);           //     16,384 B
  __bf16* w2_f   = (__bf16*)(ws + 64081920);           //     32,768 B

  k_prep <<<224, 256, 0, stream>>>(W1, W2, w1a_f, w1b_f, w1c_f, w2_f);
  k_t12f <<<(N_NODES / 16 + 3) / 4, 256, 0, stream>>>(x, ln_scale, ln_bias,
                                                      w1a_f, w1b_f, b1, t1p, t2bp);
  k_edge <<<N_NODES / 16, 256, 0, stream>>>(nbr_fea, nbr_idx, t1p, t2bp, w1c_f, hsum_p);
  k_out  <<<(N_NODES / 16 + 3) / 4, 256, 0, stream>>>(hsum_p, w2_f, b2, x, out);
}

// Round 8
// 141.711 us; speedup vs baseline: 3.7669x; 1.0840x over previous
//
#include <hip/hip_runtime.h>
#include <math.h>

#define N_NODES 50000
#define M_NBR 16
#define D 128
#define E 64

typedef __attribute__((ext_vector_type(8))) __bf16 bf16x8;
typedef __attribute__((ext_vector_type(4))) float f32x4;

// Fragment-permuted weight storage (bf16):
//   flat = (((dt*NKT + kt)*4 + c)*16 + r)*8 + j
// holds W_natural[k = kt*32 + c*8 + j][d = dt*16 + r].
// Lane (r,c) then loads one bf16x8 at vector-index (dt*NKT+kt)*64 + c*16 + r.

// ---------------------------------------------------------------------------
// K0: build fragment-permuted bf16 weights.  (unchanged, known-good)
// ---------------------------------------------------------------------------
__global__ __launch_bounds__(256) void k_prep(const float* __restrict__ W1,
                                              const float* __restrict__ W2,
                                              __bf16* __restrict__ w1a_f,
                                              __bf16* __restrict__ w1b_f,
                                              __bf16* __restrict__ w1c_f,
                                              __bf16* __restrict__ w2_f) {
  const int t = blockIdx.x * 256 + threadIdx.x;
  if (t < 16384) {                       // W1a
    const int j = t & 7, r = (t >> 3) & 15, c = (t >> 7) & 3, q = t >> 9;
    const int kt = q & 3, dt = q >> 2;
    w1a_f[t] = (__bf16)W1[(kt * 32 + c * 8 + j) * 128 + dt * 16 + r];
  } else if (t < 32768) {                // W1b
    const int u = t - 16384;
    const int j = u & 7, r = (u >> 3) & 15, c = (u >> 7) & 3, q = u >> 9;
    const int kt = q & 3, dt = q >> 2;
    w1b_f[u] = (__bf16)W1[(128 + kt * 32 + c * 8 + j) * 128 + dt * 16 + r];
  } else if (t < 40960) {                // W1c (NKT=2)
    const int u = t - 32768;
    const int j = u & 7, r = (u >> 3) & 15, c = (u >> 7) & 3, q = u >> 9;
    const int kt = q & 1, dt = q >> 1;
    w1c_f[u] = (__bf16)W1[(256 + kt * 32 + c * 8 + j) * 128 + dt * 16 + r];
  } else if (t < 57344) {                // W2, permuted k
    const int u = t - 40960;
    const int j = u & 7, r = (u >> 3) & 15, c = (u >> 7) & 3, q = u >> 9;
    const int kt = q & 3, dt = q >> 2;
    const int i = kt * 32 + c * 8 + j;             // stored-k
    const int ak = (i & 7) * 16 + (i >> 3);        // natural k in hsum row
    w2_f[u] = (__bf16)W2[ak * 128 + dt * 16 + r];
  }
}

// ---------------------------------------------------------------------------
// K1: fused LayerNorm + dual GEMM via MFMA.  (unchanged, known-good)
// ---------------------------------------------------------------------------
__global__ __launch_bounds__(256) void k_t12f(const float* __restrict__ x,
                                              const float* __restrict__ sc,
                                              const float* __restrict__ bi,
                                              const __bf16* __restrict__ w1a_f,
                                              const __bf16* __restrict__ w1b_f,
                                              const float* __restrict__ b1,
                                              float* __restrict__ t1p,
                                              __bf16* __restrict__ t2bp) {
  const int wave = blockIdx.x * 4 + (threadIdx.x >> 6);
  if (wave >= N_NODES / 16) return;
  const int lane = threadIdx.x & 63;
  const int r = lane & 15, c = lane >> 4;
  const int node0 = wave * 16;

  const float* row = x + (size_t)(node0 + r) * 128 + c * 8;
  f32x4 va[8];
  #pragma unroll
  for (int kt = 0; kt < 4; ++kt) {
    va[2 * kt]     = *(const f32x4*)(row + kt * 32);
    va[2 * kt + 1] = *(const f32x4*)(row + kt * 32 + 4);
  }
  float s = 0.f;
  #pragma unroll
  for (int q = 0; q < 8; ++q) s += va[q][0] + va[q][1] + va[q][2] + va[q][3];
  s += __shfl_xor(s, 16, 64);
  s += __shfl_xor(s, 32, 64);
  const float mu = s * (1.0f / 128.0f);
  float qs = 0.f;
  #pragma unroll
  for (int q = 0; q < 8; ++q) {
    #pragma unroll
    for (int e = 0; e < 4; ++e) { const float dxx = va[q][e] - mu; qs += dxx * dxx; }
  }
  qs += __shfl_xor(qs, 16, 64);
  qs += __shfl_xor(qs, 32, 64);
  const float rs = rsqrtf(qs * (1.0f / 128.0f) + 1e-6f);

  bf16x8 af[4];
  #pragma unroll
  for (int kt = 0; kt < 4; ++kt) {
    const f32x4 s_lo = *(const f32x4*)(sc + kt * 32 + c * 8);
    const f32x4 s_hi = *(const f32x4*)(sc + kt * 32 + c * 8 + 4);
    const f32x4 b_lo = *(const f32x4*)(bi + kt * 32 + c * 8);
    const f32x4 b_hi = *(const f32x4*)(bi + kt * 32 + c * 8 + 4);
    #pragma unroll
    for (int e = 0; e < 4; ++e) {
      af[kt][e]     = (__bf16)(((va[2 * kt][e]     - mu) * rs) * s_lo[e] + b_lo[e]);
      af[kt][4 + e] = (__bf16)(((va[2 * kt + 1][e] - mu) * rs) * s_hi[e] + b_hi[e]);
    }
  }

  const bf16x8* wa = (const bf16x8*)w1a_f;
  const bf16x8* wb = (const bf16x8*)w1b_f;
  f32x4 acc1[8], acc2[8];
  #pragma unroll
  for (int dt = 0; dt < 8; ++dt) { acc1[dt] = (f32x4){0,0,0,0}; acc2[dt] = (f32x4){0,0,0,0}; }
  #pragma unroll
  for (int dt = 0; dt < 8; ++dt) {
    #pragma unroll
    for (int kt = 0; kt < 4; ++kt) {
      const bf16x8 bfa = wa[(dt * 4 + kt) * 64 + c * 16 + r];
      acc1[dt] = __builtin_amdgcn_mfma_f32_16x16x32_bf16(af[kt], bfa, acc1[dt], 0, 0, 0);
      const bf16x8 bfb = wb[(dt * 4 + kt) * 64 + c * 16 + r];
      acc2[dt] = __builtin_amdgcn_mfma_f32_16x16x32_bf16(af[kt], bfb, acc2[dt], 0, 0, 0);
    }
  }

  float b1v[8];
  #pragma unroll
  for (int dt = 0; dt < 8; ++dt) b1v[dt] = b1[dt * 16 + r];
  #pragma unroll
  for (int j = 0; j < 4; ++j) {
    const int node = node0 + c * 4 + j;
    f32x4 t1lo, t1hi;
    bf16x8 t2v;
    #pragma unroll
    for (int dt = 0; dt < 4; ++dt)  t1lo[dt]     = acc1[dt][j] + b1v[dt];
    #pragma unroll
    for (int dt = 4; dt < 8; ++dt)  t1hi[dt - 4] = acc1[dt][j] + b1v[dt];
    #pragma unroll
    for (int dt = 0; dt < 8; ++dt)  t2v[dt] = (__bf16)acc2[dt][j];
    *(f32x4*)(t1p + (size_t)node * 128 + r * 8)     = t1lo;
    *(f32x4*)(t1p + (size_t)node * 128 + r * 8 + 4) = t1hi;
    *(bf16x8*)(t2bp + (size_t)node * 128 + r * 8)   = t2v;
  }
}

// ---------------------------------------------------------------------------
// K2: edge GEMM, R8: explicit 2-deep software pipeline.
// Named struct regs (no runtime-indexed arrays); sched_barrier(0) pins load
// issues above the following compute; __launch_bounds__(256,2) raises the
// VGPR budget so the allocator keeps both pipeline stages live.
// Fast silu via __fdividef.
// ---------------------------------------------------------------------------
struct NL {
  f32x4 lo0, hi0, lo1, hi1;      // nbr A-row pieces
  bf16x8 tg0, tg1, tg2, tg3;     // gathered t2 rows (4 edges of this c-group)
  f32x4 t1lo, t1hi;              // t1p row (b1 already folded in)
};

__device__ __forceinline__ NL load_node(const float* __restrict__ nbr,
                                        const float* __restrict__ t1p,
                                        const __bf16* __restrict__ t2bp,
                                        int n, int4 g, int r, int c) {
  NL v;
  const float* arow = nbr + (size_t)n * (M_NBR * E) + r * E + c * 8;
  v.lo0 = *(const f32x4*)(arow);
  v.hi0 = *(const f32x4*)(arow + 4);
  v.lo1 = *(const f32x4*)(arow + 32);
  v.hi1 = *(const f32x4*)(arow + 36);
  v.tg0 = *(const bf16x8*)(t2bp + (size_t)g.x * 128 + r * 8);
  v.tg1 = *(const bf16x8*)(t2bp + (size_t)g.y * 128 + r * 8);
  v.tg2 = *(const bf16x8*)(t2bp + (size_t)g.z * 128 + r * 8);
  v.tg3 = *(const bf16x8*)(t2bp + (size_t)g.w * 128 + r * 8);
  v.t1lo = *(const f32x4*)(t1p + (size_t)n * 128 + r * 8);
  v.t1hi = *(const f32x4*)(t1p + (size_t)n * 128 + r * 8 + 4);
  return v;
}

__device__ __forceinline__ void compute_node(const NL& v,
                                             const bf16x8 (&bfrag)[8][2],
                                             int n, int lane, int r,
                                             float* __restrict__ hsum_p) {
  bf16x8 af0, af1;
  #pragma unroll
  for (int e = 0; e < 4; ++e) {
    af0[e] = (__bf16)v.lo0[e]; af0[4 + e] = (__bf16)v.hi0[e];
    af1[e] = (__bf16)v.lo1[e]; af1[4 + e] = (__bf16)v.hi1[e];
  }
  f32x4 acc[8];
  #pragma unroll
  for (int dt = 0; dt < 8; ++dt) acc[dt] = (f32x4){0, 0, 0, 0};
  #pragma unroll
  for (int dt = 0; dt < 8; ++dt) {
    acc[dt] = __builtin_amdgcn_mfma_f32_16x16x32_bf16(af0, bfrag[dt][0], acc[dt], 0, 0, 0);
    acc[dt] = __builtin_amdgcn_mfma_f32_16x16x32_bf16(af1, bfrag[dt][1], acc[dt], 0, 0, 0);
  }
  float ssum[8];
  #pragma unroll
  for (int dt = 0; dt < 8; ++dt) {
    const float tb = (dt < 4) ? v.t1lo[dt & 3] : v.t1hi[dt & 3];
    float s = 0.f;
    { const float h = acc[dt][0] + tb + (float)v.tg0[dt]; s += __fdividef(h, 1.0f + __expf(-h)); }
    { const float h = acc[dt][1] + tb + (float)v.tg1[dt]; s += __fdividef(h, 1.0f + __expf(-h)); }
    { const float h = acc[dt][2] + tb + (float)v.tg2[dt]; s += __fdividef(h, 1.0f + __expf(-h)); }
    { const float h = acc[dt][3] + tb + (float)v.tg3[dt]; s += __fdividef(h, 1.0f + __expf(-h)); }
    s += __shfl_xor(s, 16, 64);
    s += __shfl_xor(s, 32, 64);
    ssum[dt] = s;
  }
  if (lane < 16) {
    f32x4 o_lo, o_hi;
    #pragma unroll
    for (int dt = 0; dt < 4; ++dt) { o_lo[dt] = ssum[dt]; o_hi[dt] = ssum[dt + 4]; }
    *(f32x4*)(hsum_p + (size_t)n * 128 + r * 8)     = o_lo;
    *(f32x4*)(hsum_p + (size_t)n * 128 + r * 8 + 4) = o_hi;
  }
}

__global__ __launch_bounds__(256, 2) void k_edge(const float* __restrict__ nbr,
                                                 const int* __restrict__ idx,
                                                 const float* __restrict__ t1p,
                                                 const __bf16* __restrict__ t2bp,
                                                 const __bf16* __restrict__ w1c_f,
                                                 float* __restrict__ hsum_p) {
  const int lane = threadIdx.x & 63;
  const int wid  = threadIdx.x >> 6;
  const int r = lane & 15, c = lane >> 4;

  const bf16x8* wc = (const bf16x8*)w1c_f;
  bf16x8 bfrag[8][2];
  #pragma unroll
  for (int dt = 0; dt < 8; ++dt) {
    bfrag[dt][0] = wc[(dt * 2 + 0) * 64 + c * 16 + r];
    bfrag[dt][1] = wc[(dt * 2 + 1) * 64 + c * 16 + r];
  }

  const int node0 = (blockIdx.x * 4 + wid) * 4;
  const int4 g0 = *(const int4*)(idx + (node0 + 0) * M_NBR + c * 4);
  const int4 g1 = *(const int4*)(idx + (node0 + 1) * M_NBR + c * 4);
  const int4 g2 = *(const int4*)(idx + (node0 + 2) * M_NBR + c * 4);
  const int4 g3 = *(const int4*)(idx + (node0 + 3) * M_NBR + c * 4);

  // ---- 2-deep pipeline: loads for node i+1/i+2 in flight under compute(i).
  NL a = load_node(nbr, t1p, t2bp, node0 + 0, g0, r, c);
  NL b = load_node(nbr, t1p, t2bp, node0 + 1, g1, r, c);
  __builtin_amdgcn_sched_barrier(0);
  compute_node(a, bfrag, node0 + 0, lane, r, hsum_p);

  a = load_node(nbr, t1p, t2bp, node0 + 2, g2, r, c);
  __builtin_amdgcn_sched_barrier(0);
  compute_node(b, bfrag, node0 + 1, lane, r, hsum_p);

  b = load_node(nbr, t1p, t2bp, node0 + 3, g3, r, c);
  __builtin_amdgcn_sched_barrier(0);
  compute_node(a, bfrag, node0 + 2, lane, r, hsum_p);
  compute_node(b, bfrag, node0 + 3, lane, r, hsum_p);
}

// ---------------------------------------------------------------------------
// K3: out = x + hsum@W2 + 16*b2 via MFMA.  (unchanged, known-good)
// ---------------------------------------------------------------------------
__global__ __launch_bounds__(256) void k_out(const float* __restrict__ hsum_p,
                                             const __bf16* __restrict__ w2_f,
                                             const float* __restrict__ b2,
                                             const float* __restrict__ x,
                                             float* __restrict__ out) {
  const int wave = blockIdx.x * 4 + (threadIdx.x >> 6);
  if (wave >= N_NODES / 16) return;
  const int lane = threadIdx.x & 63;
  const int r = lane & 15, c = lane >> 4;
  const int node0 = wave * 16;

  const float* row = hsum_p + (size_t)(node0 + r) * 128 + c * 8;
  bf16x8 af[4];
  #pragma unroll
  for (int kt = 0; kt < 4; ++kt) {
    const f32x4 lo = *(const f32x4*)(row + kt * 32);
    const f32x4 hi = *(const f32x4*)(row + kt * 32 + 4);
    #pragma unroll
    for (int e = 0; e < 4; ++e) { af[kt][e] = (__bf16)lo[e]; af[kt][4 + e] = (__bf16)hi[e]; }
  }

  const bf16x8* w2 = (const bf16x8*)w2_f;
  f32x4 acc[8];
  #pragma unroll
  for (int dt = 0; dt < 8; ++dt) acc[dt] = (f32x4){0,0,0,0};
  #pragma unroll
  for (int dt = 0; dt < 8; ++dt) {
    #pragma unroll
    for (int kt = 0; kt < 4; ++kt) {
      const bf16x8 bf = w2[(dt * 4 + kt) * 64 + c * 16 + r];
      acc[dt] = __builtin_amdgcn_mfma_f32_16x16x32_bf16(af[kt], bf, acc[dt], 0, 0, 0);
    }
  }

  float b2v[8];
  #pragma unroll
  for (int dt = 0; dt < 8; ++dt) b2v[dt] = 16.0f * b2[dt * 16 + r];
  #pragma unroll
  for (int j = 0; j < 4; ++j) {
    const int node = node0 + c * 4 + j;
    #pragma unroll
    for (int dt = 0; dt < 8; ++dt) {
      const size_t o = (size_t)node * 128 + dt * 16 + r;
      out[o] = x[o] + acc[dt][j] + b2v[dt];
    }
  }
}

// ---------------------------------------------------------------------------
extern "C" void kernel_launch(void* const* d_in, const int* in_sizes, int n_in,
                              void* d_out, int out_size, void* d_ws, size_t ws_size,
                              hipStream_t stream) {
  const float* x        = (const float*)d_in[0];
  const float* nbr_fea  = (const float*)d_in[1];
  const int*   nbr_idx  = (const int*)d_in[2];
  const float* ln_scale = (const float*)d_in[3];
  const float* ln_bias  = (const float*)d_in[4];
  const float* W1       = (const float*)d_in[5];
  const float* b1       = (const float*)d_in[6];
  const float* W2       = (const float*)d_in[7];
  const float* b2       = (const float*)d_in[8];
  float* out = (float*)d_out;

  char* ws = (char*)d_ws;
  float*  t1p    = (float*)(ws);                       // 25,600,000 B
  float*  hsum_p = (float*)(ws + 25600000);            // 25,600,000 B
  __bf16* t2bp   = (__bf16*)(ws + 51200000);           // 12,800,000 B
  __bf16* w1a_f  = (__bf16*)(ws + 64000000);           //     32,768 B
  __bf16* w1b_f  = (__bf16*)(ws + 64032768);           //     32,768 B
  __bf16* w1c_f  = (__bf16*)(ws + 64065536);           //     16,384 B
  __bf16* w2_f   = (__bf16*)(ws + 64081920);           //     32,768 B

  k_prep <<<224, 256, 0, stream>>>(W1, W2, w1a_f, w1b_f, w1c_f, w2_f);
  k_t12f <<<(N_NODES / 16 + 3) / 4, 256, 0, stream>>>(x, ln_scale, ln_bias,
                                                      w1a_f, w1b_f, b1, t1p, t2bp);
  k_edge <<<N_NODES / 16, 256, 0, stream>>>(nbr_fea, nbr_idx, t1p, t2bp, w1c_f, hsum_p);
  k_out  <<<(N_NODES / 16 + 3) / 4, 256, 0, stream>>>(hsum_p, w2_f, b2, x, out);
}

// Round 11
// 139.876 us; speedup vs baseline: 3.8163x; 1.0131x over previous
//
#include <hip/hip_runtime.h>
#include <math.h>

#define N_NODES 50000
#define M_NBR 16
#define D 128
#define E 64

typedef __attribute__((ext_vector_type(8))) __bf16 bf16x8;
typedef __attribute__((ext_vector_type(4))) float f32x4;

// async global->LDS (HW: per-lane global src; wave-uniform LDS base + lane*size)
__device__ __forceinline__ void gload16(const void* g, void* l) {
  __builtin_amdgcn_global_load_lds(
      (const __attribute__((address_space(1))) void*)g,
      (__attribute__((address_space(3))) void*)l, 16, 0, 0);
}
__device__ __forceinline__ void gload4(const void* g, void* l) {
  __builtin_amdgcn_global_load_lds(
      (const __attribute__((address_space(1))) void*)g,
      (__attribute__((address_space(3))) void*)l, 4, 0, 0);
}

// Counted VMEM wait: global_load_lds completion is tracked by vmcnt (NOT
// lgkmcnt), and the compiler does not auto-order ds_read against it.
// sched_barrier(0) on both sides pins code motion (rule #18).
#define VMWAIT(N)                                                   \
  do {                                                              \
    __builtin_amdgcn_sched_barrier(0);                              \
    asm volatile("s_waitcnt vmcnt(" #N ")" ::: "memory");           \
    __builtin_amdgcn_sched_barrier(0);                              \
  } while (0)

// Fragment-permuted weight storage (bf16):
//   flat = (((dt*NKT + kt)*4 + c)*16 + r)*8 + j
// holds W_natural[k = kt*32 + c*8 + j][d = dt*16 + r].

// ---------------------------------------------------------------------------
// K0: build fragment-permuted bf16 weights.  (unchanged, known-good)
// ---------------------------------------------------------------------------
__global__ __launch_bounds__(256) void k_prep(const float* __restrict__ W1,
                                              const float* __restrict__ W2,
                                              __bf16* __restrict__ w1a_f,
                                              __bf16* __restrict__ w1b_f,
                                              __bf16* __restrict__ w1c_f,
                                              __bf16* __restrict__ w2_f) {
  const int t = blockIdx.x * 256 + threadIdx.x;
  if (t < 16384) {                       // W1a
    const int j = t & 7, r = (t >> 3) & 15, c = (t >> 7) & 3, q = t >> 9;
    const int kt = q & 3, dt = q >> 2;
    w1a_f[t] = (__bf16)W1[(kt * 32 + c * 8 + j) * 128 + dt * 16 + r];
  } else if (t < 32768) {                // W1b
    const int u = t - 16384;
    const int j = u & 7, r = (u >> 3) & 15, c = (u >> 7) & 3, q = u >> 9;
    const int kt = q & 3, dt = q >> 2;
    w1b_f[u] = (__bf16)W1[(128 + kt * 32 + c * 8 + j) * 128 + dt * 16 + r];
  } else if (t < 40960) {                // W1c (NKT=2)
    const int u = t - 32768;
    const int j = u & 7, r = (u >> 3) & 15, c = (u >> 7) & 3, q = u >> 9;
    const int kt = q & 1, dt = q >> 1;
    w1c_f[u] = (__bf16)W1[(256 + kt * 32 + c * 8 + j) * 128 + dt * 16 + r];
  } else if (t < 57344) {                // W2, permuted k
    const int u = t - 40960;
    const int j = u & 7, r = (u >> 3) & 15, c = (u >> 7) & 3, q = u >> 9;
    const int kt = q & 3, dt = q >> 2;
    const int i = kt * 32 + c * 8 + j;             // stored-k
    const int ak = (i & 7) * 16 + (i >> 3);        // natural k in hsum row
    w2_f[u] = (__bf16)W2[ak * 128 + dt * 16 + r];
  }
}

// ---------------------------------------------------------------------------
// K1: fused LayerNorm + dual GEMM via MFMA.  (unchanged, known-good)
// ---------------------------------------------------------------------------
__global__ __launch_bounds__(256) void k_t12f(const float* __restrict__ x,
                                              const float* __restrict__ sc,
                                              const float* __restrict__ bi,
                                              const __bf16* __restrict__ w1a_f,
                                              const __bf16* __restrict__ w1b_f,
                                              const float* __restrict__ b1,
                                              float* __restrict__ t1p,
                                              __bf16* __restrict__ t2bp) {
  const int wave = blockIdx.x * 4 + (threadIdx.x >> 6);
  if (wave >= N_NODES / 16) return;
  const int lane = threadIdx.x & 63;
  const int r = lane & 15, c = lane >> 4;
  const int node0 = wave * 16;

  const float* row = x + (size_t)(node0 + r) * 128 + c * 8;
  f32x4 va[8];
  #pragma unroll
  for (int kt = 0; kt < 4; ++kt) {
    va[2 * kt]     = *(const f32x4*)(row + kt * 32);
    va[2 * kt + 1] = *(const f32x4*)(row + kt * 32 + 4);
  }
  float s = 0.f;
  #pragma unroll
  for (int q = 0; q < 8; ++q) s += va[q][0] + va[q][1] + va[q][2] + va[q][3];
  s += __shfl_xor(s, 16, 64);
  s += __shfl_xor(s, 32, 64);
  const float mu = s * (1.0f / 128.0f);
  float qs = 0.f;
  #pragma unroll
  for (int q = 0; q < 8; ++q) {
    #pragma unroll
    for (int e = 0; e < 4; ++e) { const float dxx = va[q][e] - mu; qs += dxx * dxx; }
  }
  qs += __shfl_xor(qs, 16, 64);
  qs += __shfl_xor(qs, 32, 64);
  const float rs = rsqrtf(qs * (1.0f / 128.0f) + 1e-6f);

  bf16x8 af[4];
  #pragma unroll
  for (int kt = 0; kt < 4; ++kt) {
    const f32x4 s_lo = *(const f32x4*)(sc + kt * 32 + c * 8);
    const f32x4 s_hi = *(const f32x4*)(sc + kt * 32 + c * 8 + 4);
    const f32x4 b_lo = *(const f32x4*)(bi + kt * 32 + c * 8);
    const f32x4 b_hi = *(const f32x4*)(bi + kt * 32 + c * 8 + 4);
    #pragma unroll
    for (int e = 0; e < 4; ++e) {
      af[kt][e]     = (__bf16)(((va[2 * kt][e]     - mu) * rs) * s_lo[e] + b_lo[e]);
      af[kt][4 + e] = (__bf16)(((va[2 * kt + 1][e] - mu) * rs) * s_hi[e] + b_hi[e]);
    }
  }

  const bf16x8* wa = (const bf16x8*)w1a_f;
  const bf16x8* wb = (const bf16x8*)w1b_f;
  f32x4 acc1[8], acc2[8];
  #pragma unroll
  for (int dt = 0; dt < 8; ++dt) { acc1[dt] = (f32x4){0,0,0,0}; acc2[dt] = (f32x4){0,0,0,0}; }
  #pragma unroll
  for (int dt = 0; dt < 8; ++dt) {
    #pragma unroll
    for (int kt = 0; kt < 4; ++kt) {
      const bf16x8 bfa = wa[(dt * 4 + kt) * 64 + c * 16 + r];
      acc1[dt] = __builtin_amdgcn_mfma_f32_16x16x32_bf16(af[kt], bfa, acc1[dt], 0, 0, 0);
      const bf16x8 bfb = wb[(dt * 4 + kt) * 64 + c * 16 + r];
      acc2[dt] = __builtin_amdgcn_mfma_f32_16x16x32_bf16(af[kt], bfb, acc2[dt], 0, 0, 0);
    }
  }

  float b1v[8];
  #pragma unroll
  for (int dt = 0; dt < 8; ++dt) b1v[dt] = b1[dt * 16 + r];
  #pragma unroll
  for (int j = 0; j < 4; ++j) {
    const int node = node0 + c * 4 + j;
    f32x4 t1lo, t1hi;
    bf16x8 t2v;
    #pragma unroll
    for (int dt = 0; dt < 4; ++dt)  t1lo[dt]     = acc1[dt][j] + b1v[dt];
    #pragma unroll
    for (int dt = 4; dt < 8; ++dt)  t1hi[dt - 4] = acc1[dt][j] + b1v[dt];
    #pragma unroll
    for (int dt = 0; dt < 8; ++dt)  t2v[dt] = (__bf16)acc2[dt][j];
    *(f32x4*)(t1p + (size_t)node * 128 + r * 8)     = t1lo;
    *(f32x4*)(t1p + (size_t)node * 128 + r * 8 + 4) = t1hi;
    *(bf16x8*)(t2bp + (size_t)node * 128 + r * 8)   = t2v;
  }
}

// ---------------------------------------------------------------------------
// K2: edge GEMM, R11 = R9 + counted vmcnt waits.
// Per-wave-private LDS double-buffer staging via global_load_lds; block =
// 2 waves (128 thr), no __syncthreads.  stage = 10 VMEM ops, compute
// epilogue = 2 stores; vmcnt(10) between phases keeps the prefetch in
// flight, vmcnt(2) drains the last buffer.
// Per-node buffer (8704 B):  A: 0..4096, TG: 4096..8192, T1: 8192..8704.
// ---------------------------------------------------------------------------
__device__ __forceinline__ void stage_node(const float* __restrict__ nbr,
                                           const float* __restrict__ t1p,
                                           const __bf16* __restrict__ t2bp,
                                           int n, int4 g, int r, int c,
                                           char* buf) {
  const char* an = (const char*)nbr + (size_t)n * 4096 + r * 256 + c * 32;
  gload16(an +   0, buf +    0);
  gload16(an +  16, buf + 1024);
  gload16(an + 128, buf + 2048);
  gload16(an + 144, buf + 3072);
  const char* tb = (const char*)t2bp;
  gload16(tb + (size_t)g.x * 256 + r * 16, buf + 4096);
  gload16(tb + (size_t)g.y * 256 + r * 16, buf + 5120);
  gload16(tb + (size_t)g.z * 256 + r * 16, buf + 6144);
  gload16(tb + (size_t)g.w * 256 + r * 16, buf + 7168);
  const char* t1 = (const char*)(t1p + (size_t)n * 128);
  const int lane = r + c * 16;
  gload4(t1 + lane * 4,       buf + 8192);
  gload4(t1 + 256 + lane * 4, buf + 8448);
}

__device__ __forceinline__ void compute_node(const char* buf,
                                             const bf16x8 (&bfrag)[8][2],
                                             int n, int lane, int r,
                                             float* __restrict__ hsum_p) {
  const f32x4 lo0 = *(const f32x4*)(buf +    0 + lane * 16);
  const f32x4 hi0 = *(const f32x4*)(buf + 1024 + lane * 16);
  const f32x4 lo1 = *(const f32x4*)(buf + 2048 + lane * 16);
  const f32x4 hi1 = *(const f32x4*)(buf + 3072 + lane * 16);
  const bf16x8 tg0 = *(const bf16x8*)(buf + 4096 + lane * 16);
  const bf16x8 tg1 = *(const bf16x8*)(buf + 5120 + lane * 16);
  const bf16x8 tg2 = *(const bf16x8*)(buf + 6144 + lane * 16);
  const bf16x8 tg3 = *(const bf16x8*)(buf + 7168 + lane * 16);
  const f32x4 t1lo = *(const f32x4*)(buf + 8192 + r * 32);
  const f32x4 t1hi = *(const f32x4*)(buf + 8192 + r * 32 + 16);

  bf16x8 af0, af1;
  #pragma unroll
  for (int e = 0; e < 4; ++e) {
    af0[e] = (__bf16)lo0[e]; af0[4 + e] = (__bf16)hi0[e];
    af1[e] = (__bf16)lo1[e]; af1[4 + e] = (__bf16)hi1[e];
  }
  f32x4 acc[8];
  #pragma unroll
  for (int dt = 0; dt < 8; ++dt) acc[dt] = (f32x4){0, 0, 0, 0};
  #pragma unroll
  for (int dt = 0; dt < 8; ++dt) {
    acc[dt] = __builtin_amdgcn_mfma_f32_16x16x32_bf16(af0, bfrag[dt][0], acc[dt], 0, 0, 0);
    acc[dt] = __builtin_amdgcn_mfma_f32_16x16x32_bf16(af1, bfrag[dt][1], acc[dt], 0, 0, 0);
  }
  float ssum[8];
  #pragma unroll
  for (int dt = 0; dt < 8; ++dt) {
    const float tb = (dt < 4) ? t1lo[dt & 3] : t1hi[dt & 3];
    float s = 0.f;
    { const float h = acc[dt][0] + tb + (float)tg0[dt]; s += __fdividef(h, 1.0f + __expf(-h)); }
    { const float h = acc[dt][1] + tb + (float)tg1[dt]; s += __fdividef(h, 1.0f + __expf(-h)); }
    { const float h = acc[dt][2] + tb + (float)tg2[dt]; s += __fdividef(h, 1.0f + __expf(-h)); }
    { const float h = acc[dt][3] + tb + (float)tg3[dt]; s += __fdividef(h, 1.0f + __expf(-h)); }
    s += __shfl_xor(s, 16, 64);
    s += __shfl_xor(s, 32, 64);
    ssum[dt] = s;
  }
  if (lane < 16) {
    f32x4 o_lo, o_hi;
    #pragma unroll
    for (int dt = 0; dt < 4; ++dt) { o_lo[dt] = ssum[dt]; o_hi[dt] = ssum[dt + 4]; }
    *(f32x4*)(hsum_p + (size_t)n * 128 + r * 8)     = o_lo;
    *(f32x4*)(hsum_p + (size_t)n * 128 + r * 8 + 4) = o_hi;
  }
}

__global__ __launch_bounds__(128, 2) void k_edge(const float* __restrict__ nbr,
                                                 const int* __restrict__ idx,
                                                 const float* __restrict__ t1p,
                                                 const __bf16* __restrict__ t2bp,
                                                 const __bf16* __restrict__ w1c_f,
                                                 float* __restrict__ hsum_p) {
  __shared__ char smem[2 * 2 * 8704];          // [wave][buf][8704] = 34816 B
  const int lane = threadIdx.x & 63;
  const int wid  = threadIdx.x >> 6;
  const int r = lane & 15, c = lane >> 4;
  char* bufA = smem + wid * 17408;
  char* bufB = bufA + 8704;

  const bf16x8* wc = (const bf16x8*)w1c_f;
  bf16x8 bfrag[8][2];
  #pragma unroll
  for (int dt = 0; dt < 8; ++dt) {
    bfrag[dt][0] = wc[(dt * 2 + 0) * 64 + c * 16 + r];
    bfrag[dt][1] = wc[(dt * 2 + 1) * 64 + c * 16 + r];
  }

  const int node0 = (blockIdx.x * 2 + wid) * 4;
  const int4 g0 = *(const int4*)(idx + (node0 + 0) * M_NBR + c * 4);
  const int4 g1 = *(const int4*)(idx + (node0 + 1) * M_NBR + c * 4);
  const int4 g2 = *(const int4*)(idx + (node0 + 2) * M_NBR + c * 4);
  const int4 g3 = *(const int4*)(idx + (node0 + 3) * M_NBR + c * 4);

  stage_node(nbr, t1p, t2bp, node0 + 0, g0, r, c, bufA);   // 10 VMEM
  stage_node(nbr, t1p, t2bp, node0 + 1, g1, r, c, bufB);   // 10 VMEM
  VMWAIT(10);                                              // A landed
  compute_node(bufA, bfrag, node0 + 0, lane, r, hsum_p);

  stage_node(nbr, t1p, t2bp, node0 + 2, g2, r, c, bufA);
  VMWAIT(10);                                              // B landed
  compute_node(bufB, bfrag, node0 + 1, lane, r, hsum_p);

  stage_node(nbr, t1p, t2bp, node0 + 3, g3, r, c, bufB);
  VMWAIT(10);                                              // A(n2) landed
  compute_node(bufA, bfrag, node0 + 2, lane, r, hsum_p);

  VMWAIT(2);                                               // B(n3) landed
  compute_node(bufB, bfrag, node0 + 3, lane, r, hsum_p);
}

// ---------------------------------------------------------------------------
// K3: out = x + hsum@W2 + 16*b2 via MFMA.  (unchanged, known-good)
// ---------------------------------------------------------------------------
__global__ __launch_bounds__(256) void k_out(const float* __restrict__ hsum_p,
                                             const __bf16* __restrict__ w2_f,
                                             const float* __restrict__ b2,
                                             const float* __restrict__ x,
                                             float* __restrict__ out) {
  const int wave = blockIdx.x * 4 + (threadIdx.x >> 6);
  if (wave >= N_NODES / 16) return;
  const int lane = threadIdx.x & 63;
  const int r = lane & 15, c = lane >> 4;
  const int node0 = wave * 16;

  const float* row = hsum_p + (size_t)(node0 + r) * 128 + c * 8;
  bf16x8 af[4];
  #pragma unroll
  for (int kt = 0; kt < 4; ++kt) {
    const f32x4 lo = *(const f32x4*)(row + kt * 32);
    const f32x4 hi = *(const f32x4*)(row + kt * 32 + 4);
    #pragma unroll
    for (int e = 0; e < 4; ++e) { af[kt][e] = (__bf16)lo[e]; af[kt][4 + e] = (__bf16)hi[e]; }
  }

  const bf16x8* w2 = (const bf16x8*)w2_f;
  f32x4 acc[8];
  #pragma unroll
  for (int dt = 0; dt < 8; ++dt) acc[dt] = (f32x4){0,0,0,0};
  #pragma unroll
  for (int dt = 0; dt < 8; ++dt) {
    #pragma unroll
    for (int kt = 0; kt < 4; ++kt) {
      const bf16x8 bf = w2[(dt * 4 + kt) * 64 + c * 16 + r];
      acc[dt] = __builtin_amdgcn_mfma_f32_16x16x32_bf16(af[kt], bf, acc[dt], 0, 0, 0);
    }
  }

  float b2v[8];
  #pragma unroll
  for (int dt = 0; dt < 8; ++dt) b2v[dt] = 16.0f * b2[dt * 16 + r];
  #pragma unroll
  for (int j = 0; j < 4; ++j) {
    const int node = node0 + c * 4 + j;
    #pragma unroll
    for (int dt = 0; dt < 8; ++dt) {
      const size_t o = (size_t)node * 128 + dt * 16 + r;
      out[o] = x[o] + acc[dt][j] + b2v[dt];
    }
  }
}

// ---------------------------------------------------------------------------
extern "C" void kernel_launch(void* const* d_in, const int* in_sizes, int n_in,
                              void* d_out, int out_size, void* d_ws, size_t ws_size,
                              hipStream_t stream) {
  const float* x        = (const float*)d_in[0];
  const float* nbr_fea  = (const float*)d_in[1];
  const int*   nbr_idx  = (const int*)d_in[2];
  const float* ln_scale = (const float*)d_in[3];
  const float* ln_bias  = (const float*)d_in[4];
  const float* W1       = (const float*)d_in[5];
  const float* b1       = (const float*)d_in[6];
  const float* W2       = (const float*)d_in[7];
  const float* b2       = (const float*)d_in[8];
  float* out = (float*)d_out;

  char* ws = (char*)d_ws;
  float*  t1p    = (float*)(ws);                       // 25,600,000 B
  float*  hsum_p = (float*)(ws + 25600000);            // 25,600,000 B
  __bf16* t2bp   = (__bf16*)(ws + 51200000);           // 12,800,000 B
  __bf16* w1a_f  = (__bf16*)(ws + 64000000);           //     32,768 B
  __bf16* w1b_f  = (__bf16*)(ws + 64032768);           //     32,768 B
  __bf16* w1c_f  = (__bf16*)(ws + 64065536);           //     16,384 B
  __bf16* w2_f   = (__bf16*)(ws + 64081920);           //     32,768 B

  k_prep <<<224, 256, 0, stream>>>(W1, W2, w1a_f, w1b_f, w1c_f, w2_f);
  k_t12f <<<(N_NODES / 16 + 3) / 4, 256, 0, stream>>>(x, ln_scale, ln_bias,
                                                      w1a_f, w1b_f, b1, t1p, t2bp);
  k_edge <<<N_NODES / 8, 128, 0, stream>>>(nbr_fea, nbr_idx, t1p, t2bp, w1c_f, hsum_p);
  k_out  <<<(N_NODES / 16 + 3) / 4, 256, 0, stream>>>(hsum_p, w2_f, b2, x, out);
}

// Round 12
// 131.055 us; speedup vs baseline: 4.0732x; 1.0673x over previous
//
#include <hip/hip_runtime.h>
#include <math.h>

#define N_NODES 50000
#define M_NBR 16
#define D 128
#define E 64

typedef __attribute__((ext_vector_type(8))) __bf16 bf16x8;
typedef __attribute__((ext_vector_type(4))) float f32x4;

// async global->LDS (HW: per-lane global src; wave-uniform LDS base + lane*size)
__device__ __forceinline__ void gload16(const void* g, void* l) {
  __builtin_amdgcn_global_load_lds(
      (const __attribute__((address_space(1))) void*)g,
      (__attribute__((address_space(3))) void*)l, 16, 0, 0);
}

#define SB() __builtin_amdgcn_sched_barrier(0)
// vmcnt(N)-only wait, compiler-modeled (keeps SIInsertWaitcnts' ledger
// coherent so tg-load auto-waits stay counted, not vmcnt(0) drains).
// simm16: vmcnt[3:0]=N, expcnt[6:4]=7 (no wait), lgkmcnt[13:8]=0x3F (no wait).
#if __has_builtin(__builtin_amdgcn_s_waitcnt)
#define VMWAIT(N) do { SB(); __builtin_amdgcn_s_waitcnt(0x3F70 | (N)); SB(); } while (0)
#else
#define VMWAIT(N) do { SB(); asm volatile("s_waitcnt vmcnt(" #N ")" ::: "memory"); SB(); } while (0)
#endif

// Fragment-permuted weight storage (bf16):
//   flat = (((dt*NKT + kt)*4 + c)*16 + r)*8 + j
// holds W_natural[k = kt*32 + c*8 + j][d = dt*16 + r].

// ---------------------------------------------------------------------------
// K0: build fragment-permuted bf16 weights.  (unchanged, known-good)
// ---------------------------------------------------------------------------
__global__ __launch_bounds__(256) void k_prep(const float* __restrict__ W1,
                                              const float* __restrict__ W2,
                                              __bf16* __restrict__ w1a_f,
                                              __bf16* __restrict__ w1b_f,
                                              __bf16* __restrict__ w1c_f,
                                              __bf16* __restrict__ w2_f) {
  const int t = blockIdx.x * 256 + threadIdx.x;
  if (t < 16384) {                       // W1a
    const int j = t & 7, r = (t >> 3) & 15, c = (t >> 7) & 3, q = t >> 9;
    const int kt = q & 3, dt = q >> 2;
    w1a_f[t] = (__bf16)W1[(kt * 32 + c * 8 + j) * 128 + dt * 16 + r];
  } else if (t < 32768) {                // W1b
    const int u = t - 16384;
    const int j = u & 7, r = (u >> 3) & 15, c = (u >> 7) & 3, q = u >> 9;
    const int kt = q & 3, dt = q >> 2;
    w1b_f[u] = (__bf16)W1[(128 + kt * 32 + c * 8 + j) * 128 + dt * 16 + r];
  } else if (t < 40960) {                // W1c (NKT=2)
    const int u = t - 32768;
    const int j = u & 7, r = (u >> 3) & 15, c = (u >> 7) & 3, q = u >> 9;
    const int kt = q & 1, dt = q >> 1;
    w1c_f[u] = (__bf16)W1[(256 + kt * 32 + c * 8 + j) * 128 + dt * 16 + r];
  } else if (t < 57344) {                // W2, permuted k
    const int u = t - 40960;
    const int j = u & 7, r = (u >> 3) & 15, c = (u >> 7) & 3, q = u >> 9;
    const int kt = q & 3, dt = q >> 2;
    const int i = kt * 32 + c * 8 + j;             // stored-k
    const int ak = (i & 7) * 16 + (i >> 3);        // natural k in hsum row
    w2_f[u] = (__bf16)W2[ak * 128 + dt * 16 + r];
  }
}

// ---------------------------------------------------------------------------
// K1: fused LayerNorm + dual GEMM via MFMA.  (unchanged, known-good)
// ---------------------------------------------------------------------------
__global__ __launch_bounds__(256) void k_t12f(const float* __restrict__ x,
                                              const float* __restrict__ sc,
                                              const float* __restrict__ bi,
                                              const __bf16* __restrict__ w1a_f,
                                              const __bf16* __restrict__ w1b_f,
                                              const float* __restrict__ b1,
                                              float* __restrict__ t1p,
                                              __bf16* __restrict__ t2bp) {
  const int wave = blockIdx.x * 4 + (threadIdx.x >> 6);
  if (wave >= N_NODES / 16) return;
  const int lane = threadIdx.x & 63;
  const int r = lane & 15, c = lane >> 4;
  const int node0 = wave * 16;

  const float* row = x + (size_t)(node0 + r) * 128 + c * 8;
  f32x4 va[8];
  #pragma unroll
  for (int kt = 0; kt < 4; ++kt) {
    va[2 * kt]     = *(const f32x4*)(row + kt * 32);
    va[2 * kt + 1] = *(const f32x4*)(row + kt * 32 + 4);
  }
  float s = 0.f;
  #pragma unroll
  for (int q = 0; q < 8; ++q) s += va[q][0] + va[q][1] + va[q][2] + va[q][3];
  s += __shfl_xor(s, 16, 64);
  s += __shfl_xor(s, 32, 64);
  const float mu = s * (1.0f / 128.0f);
  float qs = 0.f;
  #pragma unroll
  for (int q = 0; q < 8; ++q) {
    #pragma unroll
    for (int e = 0; e < 4; ++e) { const float dxx = va[q][e] - mu; qs += dxx * dxx; }
  }
  qs += __shfl_xor(qs, 16, 64);
  qs += __shfl_xor(qs, 32, 64);
  const float rs = rsqrtf(qs * (1.0f / 128.0f) + 1e-6f);

  bf16x8 af[4];
  #pragma unroll
  for (int kt = 0; kt < 4; ++kt) {
    const f32x4 s_lo = *(const f32x4*)(sc + kt * 32 + c * 8);
    const f32x4 s_hi = *(const f32x4*)(sc + kt * 32 + c * 8 + 4);
    const f32x4 b_lo = *(const f32x4*)(bi + kt * 32 + c * 8);
    const f32x4 b_hi = *(const f32x4*)(bi + kt * 32 + c * 8 + 4);
    #pragma unroll
    for (int e = 0; e < 4; ++e) {
      af[kt][e]     = (__bf16)(((va[2 * kt][e]     - mu) * rs) * s_lo[e] + b_lo[e]);
      af[kt][4 + e] = (__bf16)(((va[2 * kt + 1][e] - mu) * rs) * s_hi[e] + b_hi[e]);
    }
  }

  const bf16x8* wa = (const bf16x8*)w1a_f;
  const bf16x8* wb = (const bf16x8*)w1b_f;
  f32x4 acc1[8], acc2[8];
  #pragma unroll
  for (int dt = 0; dt < 8; ++dt) { acc1[dt] = (f32x4){0,0,0,0}; acc2[dt] = (f32x4){0,0,0,0}; }
  #pragma unroll
  for (int dt = 0; dt < 8; ++dt) {
    #pragma unroll
    for (int kt = 0; kt < 4; ++kt) {
      const bf16x8 bfa = wa[(dt * 4 + kt) * 64 + c * 16 + r];
      acc1[dt] = __builtin_amdgcn_mfma_f32_16x16x32_bf16(af[kt], bfa, acc1[dt], 0, 0, 0);
      const bf16x8 bfb = wb[(dt * 4 + kt) * 64 + c * 16 + r];
      acc2[dt] = __builtin_amdgcn_mfma_f32_16x16x32_bf16(af[kt], bfb, acc2[dt], 0, 0, 0);
    }
  }

  float b1v[8];
  #pragma unroll
  for (int dt = 0; dt < 8; ++dt) b1v[dt] = b1[dt * 16 + r];
  #pragma unroll
  for (int j = 0; j < 4; ++j) {
    const int node = node0 + c * 4 + j;
    f32x4 t1lo, t1hi;
    bf16x8 t2v;
    #pragma unroll
    for (int dt = 0; dt < 4; ++dt)  t1lo[dt]     = acc1[dt][j] + b1v[dt];
    #pragma unroll
    for (int dt = 4; dt < 8; ++dt)  t1hi[dt - 4] = acc1[dt][j] + b1v[dt];
    #pragma unroll
    for (int dt = 0; dt < 8; ++dt)  t2v[dt] = (__bf16)acc2[dt][j];
    *(f32x4*)(t1p + (size_t)node * 128 + r * 8)     = t1lo;
    *(f32x4*)(t1p + (size_t)node * 128 + r * 8 + 4) = t1hi;
    *(bf16x8*)(t2bp + (size_t)node * 128 + r * 8)   = t2v;
  }
}

// ---------------------------------------------------------------------------
// K2: edge GEMM, R12: A-only LDS staging (4KB/node, 8KB/wave -> LDS allows
// 20 waves/CU) + gathers/t1 direct-to-VGPR issued BEFORE the next A-stage
// (demand loads older than prefetch -> their waits never drain the pipeline;
// vmcnt is a single in-order counter).  TLP (3+ waves/SIMD) hides gather
// latency.  __launch_bounds__(128,3).
// ---------------------------------------------------------------------------
struct TG {
  bf16x8 tg0, tg1, tg2, tg3;   // gathered t2 rows (4 edges of this c-group)
  f32x4 t1lo, t1hi;            // t1p row (b1 folded in)
};

__device__ __forceinline__ TG load_tg(const float* __restrict__ t1p,
                                      const __bf16* __restrict__ t2bp,
                                      int n, int4 g, int r) {
  TG v;
  v.tg0 = *(const bf16x8*)(t2bp + (size_t)g.x * 128 + r * 8);
  v.tg1 = *(const bf16x8*)(t2bp + (size_t)g.y * 128 + r * 8);
  v.tg2 = *(const bf16x8*)(t2bp + (size_t)g.z * 128 + r * 8);
  v.tg3 = *(const bf16x8*)(t2bp + (size_t)g.w * 128 + r * 8);
  v.t1lo = *(const f32x4*)(t1p + (size_t)n * 128 + r * 8);
  v.t1hi = *(const f32x4*)(t1p + (size_t)n * 128 + r * 8 + 4);
  return v;
}

__device__ __forceinline__ void stageA(const float* __restrict__ nbr,
                                       int n, int r, int c, char* buf) {
  const char* an = (const char*)nbr + (size_t)n * 4096 + r * 256 + c * 32;
  gload16(an +   0, buf +    0);
  gload16(an +  16, buf + 1024);
  gload16(an + 128, buf + 2048);
  gload16(an + 144, buf + 3072);
}

__device__ __forceinline__ void compute_node(const char* buf, const TG& v,
                                             const bf16x8 (&bfrag)[8][2],
                                             int n, int lane, int r,
                                             float* __restrict__ hsum_p) {
  const f32x4 lo0 = *(const f32x4*)(buf +    0 + lane * 16);
  const f32x4 hi0 = *(const f32x4*)(buf + 1024 + lane * 16);
  const f32x4 lo1 = *(const f32x4*)(buf + 2048 + lane * 16);
  const f32x4 hi1 = *(const f32x4*)(buf + 3072 + lane * 16);

  bf16x8 af0, af1;
  #pragma unroll
  for (int e = 0; e < 4; ++e) {
    af0[e] = (__bf16)lo0[e]; af0[4 + e] = (__bf16)hi0[e];
    af1[e] = (__bf16)lo1[e]; af1[4 + e] = (__bf16)hi1[e];
  }
  f32x4 acc[8];
  #pragma unroll
  for (int dt = 0; dt < 8; ++dt) acc[dt] = (f32x4){0, 0, 0, 0};
  #pragma unroll
  for (int dt = 0; dt < 8; ++dt) {
    acc[dt] = __builtin_amdgcn_mfma_f32_16x16x32_bf16(af0, bfrag[dt][0], acc[dt], 0, 0, 0);
    acc[dt] = __builtin_amdgcn_mfma_f32_16x16x32_bf16(af1, bfrag[dt][1], acc[dt], 0, 0, 0);
  }
  float ssum[8];
  #pragma unroll
  for (int dt = 0; dt < 8; ++dt) {
    const float tb = (dt < 4) ? v.t1lo[dt & 3] : v.t1hi[dt & 3];
    float s = 0.f;
    { const float h = acc[dt][0] + tb + (float)v.tg0[dt]; s += __fdividef(h, 1.0f + __expf(-h)); }
    { const float h = acc[dt][1] + tb + (float)v.tg1[dt]; s += __fdividef(h, 1.0f + __expf(-h)); }
    { const float h = acc[dt][2] + tb + (float)v.tg2[dt]; s += __fdividef(h, 1.0f + __expf(-h)); }
    { const float h = acc[dt][3] + tb + (float)v.tg3[dt]; s += __fdividef(h, 1.0f + __expf(-h)); }
    s += __shfl_xor(s, 16, 64);
    s += __shfl_xor(s, 32, 64);
    ssum[dt] = s;
  }
  if (lane < 16) {
    f32x4 o_lo, o_hi;
    #pragma unroll
    for (int dt = 0; dt < 4; ++dt) { o_lo[dt] = ssum[dt]; o_hi[dt] = ssum[dt + 4]; }
    *(f32x4*)(hsum_p + (size_t)n * 128 + r * 8)     = o_lo;
    *(f32x4*)(hsum_p + (size_t)n * 128 + r * 8 + 4) = o_hi;
  }
}

__global__ __launch_bounds__(128, 3) void k_edge(const float* __restrict__ nbr,
                                                 const int* __restrict__ idx,
                                                 const float* __restrict__ t1p,
                                                 const __bf16* __restrict__ t2bp,
                                                 const __bf16* __restrict__ w1c_f,
                                                 float* __restrict__ hsum_p) {
  __shared__ char smem[2 * 2 * 4096];          // [wave][buf][4KB] = 16 KB
  const int lane = threadIdx.x & 63;
  const int wid  = threadIdx.x >> 6;
  const int r = lane & 15, c = lane >> 4;
  char* bufA = smem + wid * 8192;
  char* bufB = bufA + 4096;

  const bf16x8* wc = (const bf16x8*)w1c_f;
  bf16x8 bfrag[8][2];
  #pragma unroll
  for (int dt = 0; dt < 8; ++dt) {
    bfrag[dt][0] = wc[(dt * 2 + 0) * 64 + c * 16 + r];
    bfrag[dt][1] = wc[(dt * 2 + 1) * 64 + c * 16 + r];
  }

  const int node0 = (blockIdx.x * 2 + wid) * 4;
  const int4 g0 = *(const int4*)(idx + (node0 + 0) * M_NBR + c * 4);
  const int4 g1 = *(const int4*)(idx + (node0 + 1) * M_NBR + c * 4);
  const int4 g2 = *(const int4*)(idx + (node0 + 2) * M_NBR + c * 4);
  const int4 g3 = *(const int4*)(idx + (node0 + 3) * M_NBR + c * 4);

  // prologue: sgA0 [4] ; tg0 [6] ; sgA1 [4]  -> vmcnt(4) retires sgA0+tg0
  stageA(nbr, node0 + 0, r, c, bufA);
  TG t0 = load_tg(t1p, t2bp, node0 + 0, g0, r);
  SB();
  stageA(nbr, node0 + 1, r, c, bufB);
  VMWAIT(4);
  compute_node(bufA, t0, bfrag, node0 + 0, lane, r, hsum_p);

  // iter: tg(i) [6, demand] ; sgA(i+1) [4, prefetch] ; vmcnt(4) keeps sgA flying
  TG t1v = load_tg(t1p, t2bp, node0 + 1, g1, r);
  SB();
  stageA(nbr, node0 + 2, r, c, bufA);
  VMWAIT(4);
  compute_node(bufB, t1v, bfrag, node0 + 1, lane, r, hsum_p);

  TG t2g = load_tg(t1p, t2bp, node0 + 2, g2, r);
  SB();
  stageA(nbr, node0 + 3, r, c, bufB);
  VMWAIT(4);
  compute_node(bufA, t2g, bfrag, node0 + 2, lane, r, hsum_p);

  TG t3g = load_tg(t1p, t2bp, node0 + 3, g3, r);
  VMWAIT(0);
  compute_node(bufB, t3g, bfrag, node0 + 3, lane, r, hsum_p);
}

// ---------------------------------------------------------------------------
// K3: out = x + hsum@W2 + 16*b2 via MFMA.  (unchanged, known-good)
// ---------------------------------------------------------------------------
__global__ __launch_bounds__(256) void k_out(const float* __restrict__ hsum_p,
                                             const __bf16* __restrict__ w2_f,
                                             const float* __restrict__ b2,
                                             const float* __restrict__ x,
                                             float* __restrict__ out) {
  const int wave = blockIdx.x * 4 + (threadIdx.x >> 6);
  if (wave >= N_NODES / 16) return;
  const int lane = threadIdx.x & 63;
  const int r = lane & 15, c = lane >> 4;
  const int node0 = wave * 16;

  const float* row = hsum_p + (size_t)(node0 + r) * 128 + c * 8;
  bf16x8 af[4];
  #pragma unroll
  for (int kt = 0; kt < 4; ++kt) {
    const f32x4 lo = *(const f32x4*)(row + kt * 32);
    const f32x4 hi = *(const f32x4*)(row + kt * 32 + 4);
    #pragma unroll
    for (int e = 0; e < 4; ++e) { af[kt][e] = (__bf16)lo[e]; af[kt][4 + e] = (__bf16)hi[e]; }
  }

  const bf16x8* w2 = (const bf16x8*)w2_f;
  f32x4 acc[8];
  #pragma unroll
  for (int dt = 0; dt < 8; ++dt) acc[dt] = (f32x4){0,0,0,0};
  #pragma unroll
  for (int dt = 0; dt < 8; ++dt) {
    #pragma unroll
    for (int kt = 0; kt < 4; ++kt) {
      const bf16x8 bf = w2[(dt * 4 + kt) * 64 + c * 16 + r];
      acc[dt] = __builtin_amdgcn_mfma_f32_16x16x32_bf16(af[kt], bf, acc[dt], 0, 0, 0);
    }
  }

  float b2v[8];
  #pragma unroll
  for (int dt = 0; dt < 8; ++dt) b2v[dt] = 16.0f * b2[dt * 16 + r];
  #pragma unroll
  for (int j = 0; j < 4; ++j) {
    const int node = node0 + c * 4 + j;
    #pragma unroll
    for (int dt = 0; dt < 8; ++dt) {
      const size_t o = (size_t)node * 128 + dt * 16 + r;
      out[o] = x[o] + acc[dt][j] + b2v[dt];
    }
  }
}

// ---------------------------------------------------------------------------
extern "C" void kernel_launch(void* const* d_in, const int* in_sizes, int n_in,
                              void* d_out, int out_size, void* d_ws, size_t ws_size,
                              hipStream_t stream) {
  const float* x        = (const float*)d_in[0];
  const float* nbr_fea  = (const float*)d_in[1];
  const int*   nbr_idx  = (const int*)d_in[2];
  const float* ln_scale = (const float*)d_in[3];
  const float* ln_bias  = (const float*)d_in[4];
  const float* W1       = (const float*)d_in[5];
  const float* b1       = (const float*)d_in[6];
  const float* W2       = (const float*)d_in[7];
  const float* b2       = (const float*)d_in[8];
  float* out = (float*)d_out;

  char* ws = (char*)d_ws;
  float*  t1p    = (float*)(ws);                       // 25,600,000 B
  float*  hsum_p = (float*)(ws + 25600000);            // 25,600,000 B
  __bf16* t2bp   = (__bf16*)(ws + 51200000);           // 12,800,000 B
  __bf16* w1a_f  = (__bf16*)(ws + 64000000);           //     32,768 B
  __bf16* w1b_f  = (__bf16*)(ws + 64032768);           //     32,768 B
  __bf16* w1c_f  = (__bf16*)(ws + 64065536);           //     16,384 B
  __bf16* w2_f   = (__bf16*)(ws + 64081920);           //     32,768 B

  k_prep <<<224, 256, 0, stream>>>(W1, W2, w1a_f, w1b_f, w1c_f, w2_f);
  k_t12f <<<(N_NODES / 16 + 3) / 4, 256, 0, stream>>>(x, ln_scale, ln_bias,
                                                      w1a_f, w1b_f, b1, t1p, t2bp);
  k_edge <<<N_NODES / 8, 128, 0, stream>>>(nbr_fea, nbr_idx, t1p, t2bp, w1c_f, hsum_p);
  k_out  <<<(N_NODES / 16 + 3) / 4, 256, 0, stream>>>(hsum_p, w2_f, b2, x, out);
}

// Round 13
// 129.703 us; speedup vs baseline: 4.1156x; 1.0104x over previous
//
#include <hip/hip_runtime.h>
#include <math.h>

#define N_NODES 50000
#define M_NBR 16
#define D 128
#define E 64

typedef __attribute__((ext_vector_type(8))) __bf16 bf16x8;
typedef __attribute__((ext_vector_type(4))) float f32x4;

// async global->LDS (HW: per-lane global src; wave-uniform LDS base + lane*16)
__device__ __forceinline__ void gload16(const void* g, void* l) {
  __builtin_amdgcn_global_load_lds(
      (const __attribute__((address_space(1))) void*)g,
      (__attribute__((address_space(3))) void*)l, 16, 0, 0);
}

// Fragment-permuted weight storage (bf16):
//   flat = (((dt*NKT + kt)*4 + c)*16 + r)*8 + j
// holds W_natural[k = kt*32 + c*8 + j][d = dt*16 + r].

// ---------------------------------------------------------------------------
// K0: build fragment-permuted bf16 weights.  (unchanged, known-good)
// ---------------------------------------------------------------------------
__global__ __launch_bounds__(256) void k_prep(const float* __restrict__ W1,
                                              const float* __restrict__ W2,
                                              __bf16* __restrict__ w1a_f,
                                              __bf16* __restrict__ w1b_f,
                                              __bf16* __restrict__ w1c_f,
                                              __bf16* __restrict__ w2_f) {
  const int t = blockIdx.x * 256 + threadIdx.x;
  if (t < 16384) {                       // W1a
    const int j = t & 7, r = (t >> 3) & 15, c = (t >> 7) & 3, q = t >> 9;
    const int kt = q & 3, dt = q >> 2;
    w1a_f[t] = (__bf16)W1[(kt * 32 + c * 8 + j) * 128 + dt * 16 + r];
  } else if (t < 32768) {                // W1b
    const int u = t - 16384;
    const int j = u & 7, r = (u >> 3) & 15, c = (u >> 7) & 3, q = u >> 9;
    const int kt = q & 3, dt = q >> 2;
    w1b_f[u] = (__bf16)W1[(128 + kt * 32 + c * 8 + j) * 128 + dt * 16 + r];
  } else if (t < 40960) {                // W1c (NKT=2)
    const int u = t - 32768;
    const int j = u & 7, r = (u >> 3) & 15, c = (u >> 7) & 3, q = u >> 9;
    const int kt = q & 1, dt = q >> 1;
    w1c_f[u] = (__bf16)W1[(256 + kt * 32 + c * 8 + j) * 128 + dt * 16 + r];
  } else if (t < 57344) {                // W2, permuted k
    const int u = t - 40960;
    const int j = u & 7, r = (u >> 3) & 15, c = (u >> 7) & 3, q = u >> 9;
    const int kt = q & 3, dt = q >> 2;
    const int i = kt * 32 + c * 8 + j;             // stored-k
    const int ak = (i & 7) * 16 + (i >> 3);        // natural k in hsum row
    w2_f[u] = (__bf16)W2[ak * 128 + dt * 16 + r];
  }
}

// ---------------------------------------------------------------------------
// K1: fused LayerNorm + dual GEMM via MFMA.  (unchanged, known-good)
// ---------------------------------------------------------------------------
__global__ __launch_bounds__(256) void k_t12f(const float* __restrict__ x,
                                              const float* __restrict__ sc,
                                              const float* __restrict__ bi,
                                              const __bf16* __restrict__ w1a_f,
                                              const __bf16* __restrict__ w1b_f,
                                              const float* __restrict__ b1,
                                              float* __restrict__ t1p,
                                              __bf16* __restrict__ t2bp) {
  const int wave = blockIdx.x * 4 + (threadIdx.x >> 6);
  if (wave >= N_NODES / 16) return;
  const int lane = threadIdx.x & 63;
  const int r = lane & 15, c = lane >> 4;
  const int node0 = wave * 16;

  const float* row = x + (size_t)(node0 + r) * 128 + c * 8;
  f32x4 va[8];
  #pragma unroll
  for (int kt = 0; kt < 4; ++kt) {
    va[2 * kt]     = *(const f32x4*)(row + kt * 32);
    va[2 * kt + 1] = *(const f32x4*)(row + kt * 32 + 4);
  }
  float s = 0.f;
  #pragma unroll
  for (int q = 0; q < 8; ++q) s += va[q][0] + va[q][1] + va[q][2] + va[q][3];
  s += __shfl_xor(s, 16, 64);
  s += __shfl_xor(s, 32, 64);
  const float mu = s * (1.0f / 128.0f);
  float qs = 0.f;
  #pragma unroll
  for (int q = 0; q < 8; ++q) {
    #pragma unroll
    for (int e = 0; e < 4; ++e) { const float dxx = va[q][e] - mu; qs += dxx * dxx; }
  }
  qs += __shfl_xor(qs, 16, 64);
  qs += __shfl_xor(qs, 32, 64);
  const float rs = rsqrtf(qs * (1.0f / 128.0f) + 1e-6f);

  bf16x8 af[4];
  #pragma unroll
  for (int kt = 0; kt < 4; ++kt) {
    const f32x4 s_lo = *(const f32x4*)(sc + kt * 32 + c * 8);
    const f32x4 s_hi = *(const f32x4*)(sc + kt * 32 + c * 8 + 4);
    const f32x4 b_lo = *(const f32x4*)(bi + kt * 32 + c * 8);
    const f32x4 b_hi = *(const f32x4*)(bi + kt * 32 + c * 8 + 4);
    #pragma unroll
    for (int e = 0; e < 4; ++e) {
      af[kt][e]     = (__bf16)(((va[2 * kt][e]     - mu) * rs) * s_lo[e] + b_lo[e]);
      af[kt][4 + e] = (__bf16)(((va[2 * kt + 1][e] - mu) * rs) * s_hi[e] + b_hi[e]);
    }
  }

  const bf16x8* wa = (const bf16x8*)w1a_f;
  const bf16x8* wb = (const bf16x8*)w1b_f;
  f32x4 acc1[8], acc2[8];
  #pragma unroll
  for (int dt = 0; dt < 8; ++dt) { acc1[dt] = (f32x4){0,0,0,0}; acc2[dt] = (f32x4){0,0,0,0}; }
  #pragma unroll
  for (int dt = 0; dt < 8; ++dt) {
    #pragma unroll
    for (int kt = 0; kt < 4; ++kt) {
      const bf16x8 bfa = wa[(dt * 4 + kt) * 64 + c * 16 + r];
      acc1[dt] = __builtin_amdgcn_mfma_f32_16x16x32_bf16(af[kt], bfa, acc1[dt], 0, 0, 0);
      const bf16x8 bfb = wb[(dt * 4 + kt) * 64 + c * 16 + r];
      acc2[dt] = __builtin_amdgcn_mfma_f32_16x16x32_bf16(af[kt], bfb, acc2[dt], 0, 0, 0);
    }
  }

  float b1v[8];
  #pragma unroll
  for (int dt = 0; dt < 8; ++dt) b1v[dt] = b1[dt * 16 + r];
  #pragma unroll
  for (int j = 0; j < 4; ++j) {
    const int node = node0 + c * 4 + j;
    f32x4 t1lo, t1hi;
    bf16x8 t2v;
    #pragma unroll
    for (int dt = 0; dt < 4; ++dt)  t1lo[dt]     = acc1[dt][j] + b1v[dt];
    #pragma unroll
    for (int dt = 4; dt < 8; ++dt)  t1hi[dt - 4] = acc1[dt][j] + b1v[dt];
    #pragma unroll
    for (int dt = 0; dt < 8; ++dt)  t2v[dt] = (__bf16)acc2[dt][j];
    *(f32x4*)(t1p + (size_t)node * 128 + r * 8)     = t1lo;
    *(f32x4*)(t1p + (size_t)node * 128 + r * 8 + 4) = t1hi;
    *(bf16x8*)(t2bp + (size_t)node * 128 + r * 8)   = t2v;
  }
}

// ---------------------------------------------------------------------------
// K2: edge GEMM, R13: ONE NODE PER WAVE, zero loops, maximal TLP.
// W1c staged once per 4-wave block into LDS (16KB, read via ds_read_b128,
// frees 64 bfrag VGPRs).  Per wave: issue idx/A/t1 (pre-barrier, overlap
// with W1c stage), barrier, issue tg gathers, MFMA from LDS, silu epilogue,
// store, retire.  ~2 latency windows per wave; latency hidden by wave churn.
// ---------------------------------------------------------------------------
__global__ __launch_bounds__(256, 4) void k_edge(const float* __restrict__ nbr,
                                                 const int* __restrict__ idx,
                                                 const float* __restrict__ t1p,
                                                 const __bf16* __restrict__ t2bp,
                                                 const __bf16* __restrict__ w1c_f,
                                                 float* __restrict__ hsum_p) {
  __shared__ __bf16 wlds[8192];                 // 16 KB W1c, fragment order
  const int lane = threadIdx.x & 63;
  const int wid  = threadIdx.x >> 6;
  const int r = lane & 15, c = lane >> 4;

  // ---- stage W1c -> LDS (each wave: 4 rounds x 1KB, disjoint)
  {
    const char* src = (const char*)w1c_f + wid * 1024 + lane * 16;
    char* dst = (char*)wlds + wid * 1024;       // wave-uniform base
    #pragma unroll
    for (int q = 0; q < 4; ++q) gload16(src + q * 4096, dst + q * 4096);
  }

  // ---- this wave's node: issue all independent loads pre-barrier
  const int n = blockIdx.x * 4 + wid;
  const int4 g = *(const int4*)(idx + n * M_NBR + c * 4);
  const float* arow = nbr + (size_t)n * (M_NBR * E) + r * E + c * 8;
  const f32x4 a0 = *(const f32x4*)(arow);
  const f32x4 a1 = *(const f32x4*)(arow + 4);
  const f32x4 a2 = *(const f32x4*)(arow + 32);
  const f32x4 a3 = *(const f32x4*)(arow + 36);
  const f32x4 t1lo = *(const f32x4*)(t1p + (size_t)n * 128 + r * 8);
  const f32x4 t1hi = *(const f32x4*)(t1p + (size_t)n * 128 + r * 8 + 4);

  __syncthreads();                              // drains W1c stage (+ our loads)

  // ---- gathers (issued now; consumed after the MFMA block)
  const bf16x8 tg0 = *(const bf16x8*)(t2bp + (size_t)g.x * 128 + r * 8);
  const bf16x8 tg1 = *(const bf16x8*)(t2bp + (size_t)g.y * 128 + r * 8);
  const bf16x8 tg2 = *(const bf16x8*)(t2bp + (size_t)g.z * 128 + r * 8);
  const bf16x8 tg3 = *(const bf16x8*)(t2bp + (size_t)g.w * 128 + r * 8);

  // ---- A fragments
  bf16x8 af0, af1;
  #pragma unroll
  for (int e = 0; e < 4; ++e) {
    af0[e] = (__bf16)a0[e]; af0[4 + e] = (__bf16)a1[e];
    af1[e] = (__bf16)a2[e]; af1[4 + e] = (__bf16)a3[e];
  }

  // ---- MFMAs fed from LDS (compiler pipelines ds_read vs MFMA via lgkmcnt)
  const bf16x8* wl = (const bf16x8*)wlds;
  f32x4 acc[8];
  #pragma unroll
  for (int dt = 0; dt < 8; ++dt) acc[dt] = (f32x4){0, 0, 0, 0};
  #pragma unroll
  for (int dt = 0; dt < 8; ++dt) {
    const bf16x8 b0 = wl[(dt * 2 + 0) * 64 + c * 16 + r];
    const bf16x8 b1 = wl[(dt * 2 + 1) * 64 + c * 16 + r];
    acc[dt] = __builtin_amdgcn_mfma_f32_16x16x32_bf16(af0, b0, acc[dt], 0, 0, 0);
    acc[dt] = __builtin_amdgcn_mfma_f32_16x16x32_bf16(af1, b1, acc[dt], 0, 0, 0);
  }

  // ---- epilogue: +t1(+b1) +t2[g], silu, reduce over c-groups, store
  float ssum[8];
  #pragma unroll
  for (int dt = 0; dt < 8; ++dt) {
    const float tb = (dt < 4) ? t1lo[dt & 3] : t1hi[dt & 3];
    float s = 0.f;
    { const float h = acc[dt][0] + tb + (float)tg0[dt]; s += __fdividef(h, 1.0f + __expf(-h)); }
    { const float h = acc[dt][1] + tb + (float)tg1[dt]; s += __fdividef(h, 1.0f + __expf(-h)); }
    { const float h = acc[dt][2] + tb + (float)tg2[dt]; s += __fdividef(h, 1.0f + __expf(-h)); }
    { const float h = acc[dt][3] + tb + (float)tg3[dt]; s += __fdividef(h, 1.0f + __expf(-h)); }
    s += __shfl_xor(s, 16, 64);
    s += __shfl_xor(s, 32, 64);
    ssum[dt] = s;
  }
  if (lane < 16) {
    f32x4 o_lo, o_hi;
    #pragma unroll
    for (int dt = 0; dt < 4; ++dt) { o_lo[dt] = ssum[dt]; o_hi[dt] = ssum[dt + 4]; }
    *(f32x4*)(hsum_p + (size_t)n * 128 + r * 8)     = o_lo;
    *(f32x4*)(hsum_p + (size_t)n * 128 + r * 8 + 4) = o_hi;
  }
}

// ---------------------------------------------------------------------------
// K3: out = x + hsum@W2 + 16*b2 via MFMA.  (unchanged, known-good)
// ---------------------------------------------------------------------------
__global__ __launch_bounds__(256) void k_out(const float* __restrict__ hsum_p,
                                             const __bf16* __restrict__ w2_f,
                                             const float* __restrict__ b2,
                                             const float* __restrict__ x,
                                             float* __restrict__ out) {
  const int wave = blockIdx.x * 4 + (threadIdx.x >> 6);
  if (wave >= N_NODES / 16) return;
  const int lane = threadIdx.x & 63;
  const int r = lane & 15, c = lane >> 4;
  const int node0 = wave * 16;

  const float* row = hsum_p + (size_t)(node0 + r) * 128 + c * 8;
  bf16x8 af[4];
  #pragma unroll
  for (int kt = 0; kt < 4; ++kt) {
    const f32x4 lo = *(const f32x4*)(row + kt * 32);
    const f32x4 hi = *(const f32x4*)(row + kt * 32 + 4);
    #pragma unroll
    for (int e = 0; e < 4; ++e) { af[kt][e] = (__bf16)lo[e]; af[kt][4 + e] = (__bf16)hi[e]; }
  }

  const bf16x8* w2 = (const bf16x8*)w2_f;
  f32x4 acc[8];
  #pragma unroll
  for (int dt = 0; dt < 8; ++dt) acc[dt] = (f32x4){0,0,0,0};
  #pragma unroll
  for (int dt = 0; dt < 8; ++dt) {
    #pragma unroll
    for (int kt = 0; kt < 4; ++kt) {
      const bf16x8 bf = w2[(dt * 4 + kt) * 64 + c * 16 + r];
      acc[dt] = __builtin_amdgcn_mfma_f32_16x16x32_bf16(af[kt], bf, acc[dt], 0, 0, 0);
    }
  }

  float b2v[8];
  #pragma unroll
  for (int dt = 0; dt < 8; ++dt) b2v[dt] = 16.0f * b2[dt * 16 + r];
  #pragma unroll
  for (int j = 0; j < 4; ++j) {
    const int node = node0 + c * 4 + j;
    #pragma unroll
    for (int dt = 0; dt < 8; ++dt) {
      const size_t o = (size_t)node * 128 + dt * 16 + r;
      out[o] = x[o] + acc[dt][j] + b2v[dt];
    }
  }
}

// ---------------------------------------------------------------------------
extern "C" void kernel_launch(void* const* d_in, const int* in_sizes, int n_in,
                              void* d_out, int out_size, void* d_ws, size_t ws_size,
                              hipStream_t stream) {
  const float* x        = (const float*)d_in[0];
  const float* nbr_fea  = (const float*)d_in[1];
  const int*   nbr_idx  = (const int*)d_in[2];
  const float* ln_scale = (const float*)d_in[3];
  const float* ln_bias  = (const float*)d_in[4];
  const float* W1       = (const float*)d_in[5];
  const float* b1       = (const float*)d_in[6];
  const float* W2       = (const float*)d_in[7];
  const float* b2       = (const float*)d_in[8];
  float* out = (float*)d_out;

  char* ws = (char*)d_ws;
  float*  t1p    = (float*)(ws);                       // 25,600,000 B
  float*  hsum_p = (float*)(ws + 25600000);            // 25,600,000 B
  __bf16* t2bp   = (__bf16*)(ws + 51200000);           // 12,800,000 B
  __bf16* w1a_f  = (__bf16*)(ws + 64000000);           //     32,768 B
  __bf16* w1b_f  = (__bf16*)(ws + 64032768);           //     32,768 B
  __bf16* w1c_f  = (__bf16*)(ws + 64065536);           //     16,384 B
  __bf16* w2_f   = (__bf16*)(ws + 64081920);           //     32,768 B

  k_prep <<<224, 256, 0, stream>>>(W1, W2, w1a_f, w1b_f, w1c_f, w2_f);
  k_t12f <<<(N_NODES / 16 + 3) / 4, 256, 0, stream>>>(x, ln_scale, ln_bias,
                                                      w1a_f, w1b_f, b1, t1p, t2bp);
  k_edge <<<N_NODES / 4, 256, 0, stream>>>(nbr_fea, nbr_idx, t1p, t2bp, w1c_f, hsum_p);
  k_out  <<<(N_NODES / 16 + 3) / 4, 256, 0, stream>>>(hsum_p, w2_f, b2, x, out);
}